// Round 5
// baseline (173.321 us; speedup 1.0000x reference)
//
#include <hip/hip_runtime.h>
#include <hip/hip_bf16.h>

typedef __attribute__((ext_vector_type(8))) short bf16x8;
typedef __attribute__((ext_vector_type(4))) float f32x4;
typedef __attribute__((ext_vector_type(4))) unsigned int u32x4;
typedef __attribute__((ext_vector_type(2))) unsigned int u32x2;

#define NB 2048
#define FC1_KC 1568   // K per kh-chunk (12544/8)

static __device__ __forceinline__ unsigned short f2bf(float f) {
  unsigned int u = __builtin_bit_cast(unsigned int, f);
  u += 0x7fffu + ((u >> 16) & 1u);   // RNE
  return (unsigned short)(u >> 16);
}
// HW packed f32->bf16 (RNE), two values into one dword
static __device__ __forceinline__ unsigned int cvtpk(float lo, float hi) {
  unsigned int r;
  asm("v_cvt_pk_bf16_f32 %0, %1, %2" : "=v"(r) : "v"(lo), "v"(hi));
  return r;
}

// ---------------- weight prep (single pass, vectorized fc1w) ----------------
// gid < 401408          : fc1wb[4*gid .. 4*gid+3]  (float4 -> 2x cvt_pk)
// next 18432            : w2b[kk][cout][cin]
// next 1024             : k1b[cout][tap32] (DCLS dense kernel, bf16)
__global__ __launch_bounds__(256) void k_prep(
    const float* __restrict__ w2, const float* __restrict__ fc1w,
    const float* __restrict__ w1, const float* __restrict__ p1,
    const float* __restrict__ p2,
    unsigned short* __restrict__ w2b, unsigned short* __restrict__ fc1wb,
    unsigned short* __restrict__ k1b) {
  const int gid = blockIdx.x * blockDim.x + threadIdx.x;
  if (gid < 401408) {
    f32x4 v = *(const f32x4*)&fc1w[gid*4];
    u32x2 r = { cvtpk(v[0], v[1]), cvtpk(v[2], v[3]) };
    *(u32x2*)&fc1wb[gid*4] = r;
  } else if (gid < 401408 + 18432) {
    int i = gid - 401408;
    int cin = i & 31;
    int cout = (i >> 5) & 63;
    int kk = i >> 11;          // 0..8
    int ky = kk / 3, kx = kk % 3;
    w2b[i] = f2bf(w2[((cout*32 + cin)*3 + ky)*3 + kx]);
  } else if (gid < 401408 + 18432 + 1024) {
    int t = gid - (401408 + 18432);  // 0..1023
    int o = t >> 5, tap = t & 31;
    unsigned short r = 0;
    if (tap < 25) {
      int a = tap / 5, bcol = tap % 5;
      float acc = 0.f;
      for (int k = 0; k < 26; ++k) {
        float q1 = p1[o*26 + k] + 2.0f;
        float q2 = p2[o*26 + k] + 2.0f;
        float f1 = floorf(q1), f2 = floorf(q2);
        int idx1 = (int)f1 + ((q1 - f1) >= 0.5f ? 1 : 0);
        int idx2 = (int)f2 + ((q2 - f2) >= 0.5f ? 1 : 0);
        if (idx1 == a && idx2 == bcol) acc += w1[o*26 + k];
      }
      r = f2bf(acc);
    }
    k1b[t] = r;
  }
}

// ---------------- fused conv1(MFMA)+relu -> conv2(MFMA)+relu+maxpool ----------------
// one block = one image; 4 blocks/CU (LDS 37.4 KB, VGPR<=128); 2 y-halves
// h1s layout: pixel-major, 4x 16B cin-blocks per pixel, XOR-swizzled:
//   elem(pixel, cin) -> pixel*32 + ((cin>>3) ^ ((pixel>>1)&3))*8 + (cin&7)
__global__ __launch_bounds__(256, 4) void k_conv(
    const float* __restrict__ x, const unsigned short* __restrict__ k1b,
    const float* __restrict__ b1, const unsigned short* __restrict__ w2b,
    const float* __restrict__ b2, unsigned short* __restrict__ h3) {
  __shared__ __align__(16) float xs[32*36];              // padded input, stride 36
  __shared__ __align__(16) unsigned short h1s[16*32*32]; // one y-half, swizzled

  const int t = threadIdx.x;
  const int bimg = blockIdx.x;
  const int lane = t & 63;
  const int wid = t >> 6;
  const int l15 = lane & 15;
  const int lk = lane >> 4;

  // ---- stage x into xs (zero border) ----
  for (int i = t; i < 1152; i += 256) {
    int iy = i / 36, ix = i - iy*36;
    float v = 0.f;
    if (iy >= 2 && iy < 30 && ix >= 2 && ix < 30)
      v = x[bimg*784 + (iy-2)*28 + (ix-2)];
    xs[i] = v;
  }

  // ---- conv1 operands (registers) ----
  int off[8];                       // per-lane im2col tap offsets (taps>=25 clamp: A rows are 0 there)
  #pragma unroll
  for (int j = 0; j < 8; ++j) {
    int tp = lk*8 + j; tp = tp > 24 ? 24 : tp;
    int ky = tp / 5;
    off[j] = ky*36 + (tp - ky*5);
  }
  const bf16x8 k1a0 = *(const bf16x8*)&k1b[l15*32 + lk*8];
  const bf16x8 k1a1 = *(const bf16x8*)&k1b[(16 + l15)*32 + lk*8];
  float b1v[2][4];
  #pragma unroll
  for (int nt = 0; nt < 2; ++nt)
    #pragma unroll
    for (int r = 0; r < 4; ++r)
      b1v[nt][r] = b1[nt*16 + lk*4 + r];

  // ---- conv2 operands (registers) ----
  const int ntp = wid & 1;      // couts ntp*32 .. ntp*32+31
  const int tx  = wid >> 1;     // x half-tile (wave-uniform)
  bf16x8 bfr[2][9];
  #pragma unroll
  for (int nn = 0; nn < 2; ++nn)
    #pragma unroll
    for (int kk = 0; kk < 9; ++kk)
      bfr[nn][kk] = *(const bf16x8*)&w2b[(kk*64 + (ntp*2+nn)*16 + l15)*32 + lk*8];
  float b2v[2];
  b2v[0] = b2[ntp*32 + l15];
  b2v[1] = b2[ntp*32 + 16 + l15];
  int colOff[3];                // byte offsets into an h1s row (swizzle is row-independent)
  #pragma unroll
  for (int kx = 0; kx < 3; ++kx) {
    int xk = tx*16 + l15 + kx; xk = xk > 31 ? 31 : xk;   // clamped dummies read zero pads
    colOff[kx] = xk*64 + ((lk ^ ((xk >> 1) & 3)) << 4);
  }

  __syncthreads();

  for (int half = 0; half < 2; ++half) {
    if (half) __syncthreads();          // prev half's conv2 reads done

    // ---- zero pads for this half ----
    {
      u32x4* H = (u32x4*)h1s;
      u32x4 z = {0u,0u,0u,0u};
      const int zrow = half ? 15 : 0;   // full zero row (y'=0 / y'=29)
      if (t < 128) H[zrow*128 + t] = z;
      const int r0 = half ? 0 : 1;      // col pads on the 15 computed rows
      if (t < 240) {                    // 15 rows x 4 px x 4 chunks
        int rr = t >> 4, rem = t & 15;
        int pi = rem >> 2, sub = rem & 3;
        int px = pi == 0 ? 0 : 28 + pi; // x' in {0,29,30,31}
        H[((r0 + rr)*32 + px)*4 + sub] = z;
      }
    }

    // ---- conv1 via MFMA: A=k1[cout][tap], B=im2col[tap][pixel] ----
    const int ybase = half ? 13 : 0;
    for (int tid = wid; tid < 30; tid += 4) {
      const int ty = tid >> 1;                 // 0..14
      const int x0 = (tid & 1) << 4;
      const int yo = ybase + ty;               // conv output row
      const float* bp = &xs[yo*36 + x0 + l15];
      u32x4 bw;
      bw[0] = cvtpk(bp[off[0]], bp[off[1]]);
      bw[1] = cvtpk(bp[off[2]], bp[off[3]]);
      bw[2] = cvtpk(bp[off[4]], bp[off[5]]);
      bw[3] = cvtpk(bp[off[6]], bp[off[7]]);
      const bf16x8 bfrag = __builtin_bit_cast(bf16x8, bw);
      f32x4 d0 = {0.f,0.f,0.f,0.f}, d1 = {0.f,0.f,0.f,0.f};
      d0 = __builtin_amdgcn_mfma_f32_16x16x32_bf16(k1a0, bfrag, d0, 0, 0, 0);
      d1 = __builtin_amdgcn_mfma_f32_16x16x32_bf16(k1a1, bfrag, d1, 0, 0, 0);
      // D: col=l15=pixel, row=lk*4+reg=cout -> 4 consecutive couts per lane
      const int xo = x0 + l15;
      if (xo < 28) {
        const int ry = half ? (yo - 13) : (yo + 1);
        const int pix = ry*32 + xo + 1;
        const int swz = (pix >> 1) & 3;
        const int blkbase = (lk >> 1);
        unsigned int w0lo = cvtpk(fmaxf(d0[0] + b1v[0][0], 0.f), fmaxf(d0[1] + b1v[0][1], 0.f));
        unsigned int w0hi = cvtpk(fmaxf(d0[2] + b1v[0][2], 0.f), fmaxf(d0[3] + b1v[0][3], 0.f));
        unsigned int w1lo = cvtpk(fmaxf(d1[0] + b1v[1][0], 0.f), fmaxf(d1[1] + b1v[1][1], 0.f));
        unsigned int w1hi = cvtpk(fmaxf(d1[2] + b1v[1][2], 0.f), fmaxf(d1[3] + b1v[1][3], 0.f));
        char* base = (char*)h1s + pix*64 + (lk & 1)*8;
        *(u32x2*)(base + ((blkbase ^ swz) << 4))       = (u32x2){w0lo, w0hi};
        *(u32x2*)(base + (((2 + blkbase) ^ swz) << 4)) = (u32x2){w1lo, w1hi};
      }
    }
    __syncthreads();

    // ---- conv2 via MFMA ----
    const char* h1c = (const char*)h1s;
    for (int pyl = 0; pyl < 7; ++pyl) {
      const int py = half*7 + pyl;
      const int rbase = (2*py - (half ? 14 : 0)) * 2048;
      f32x4 acc[2][2];
      #pragma unroll
      for (int yi = 0; yi < 2; ++yi)
        #pragma unroll
        for (int nn = 0; nn < 2; ++nn) acc[yi][nn] = (f32x4){0.f,0.f,0.f,0.f};
      #pragma unroll
      for (int kx = 0; kx < 3; ++kx) {
        bf16x8 af[4];
        #pragma unroll
        for (int r = 0; r < 4; ++r)
          af[r] = *(const bf16x8*)(h1c + rbase + r*2048 + colOff[kx]);
        #pragma unroll
        for (int ky = 0; ky < 3; ++ky)
          #pragma unroll
          for (int yi = 0; yi < 2; ++yi) {
            acc[yi][0] = __builtin_amdgcn_mfma_f32_16x16x32_bf16(af[yi+ky], bfr[0][ky*3+kx], acc[yi][0], 0, 0, 0);
            acc[yi][1] = __builtin_amdgcn_mfma_f32_16x16x32_bf16(af[yi+ky], bfr[1][ky*3+kx], acc[yi][1], 0, 0, 0);
          }
      }
      // bias + relu + 2x2 maxpool in-register, write bf16
      float hm[2][2][2];   // [nn][yi][xpair]
      #pragma unroll
      for (int yi = 0; yi < 2; ++yi)
        #pragma unroll
        for (int nn = 0; nn < 2; ++nn) {
          float v0 = fmaxf(acc[yi][nn][0] + b2v[nn], 0.f);
          float v1 = fmaxf(acc[yi][nn][1] + b2v[nn], 0.f);
          float v2 = fmaxf(acc[yi][nn][2] + b2v[nn], 0.f);
          float v3 = fmaxf(acc[yi][nn][3] + b2v[nn], 0.f);
          hm[nn][yi][0] = fmaxf(v0, v1);
          hm[nn][yi][1] = fmaxf(v2, v3);
        }
      if (!(tx == 1 && lk == 3)) {                 // drop x>=28 dummy columns
        const int px0 = tx*8 + lk*2;
        #pragma unroll
        for (int nn = 0; nn < 2; ++nn) {
          float q0 = fmaxf(hm[nn][0][0], hm[nn][1][0]);
          float q1 = fmaxf(hm[nn][0][1], hm[nn][1][1]);
          const int c = ntp*32 + nn*16 + l15;
          *(unsigned int*)&h3[((size_t)(bimg*64 + c)*14 + py)*14 + px0] = cvtpk(q0, q1);
        }
      }
    }
  }
}

// ---------------- fused FC1 GEMM + FC2 ----------------
// grid 256 = mtile(128) x nhalf(2). Block: 16 batch rows, 64 n, full K=12544
// (8 kh-chunks staged to LDS, acc in regs). Epilogue: bias+relu -> LDS,
// 64-wide fc2 partial dot, atomicAdd into out (2 commutative addends -> deterministic).
// As swizzled in 16B blocks: row r, block b at slot b ^ (r&7) (b<192; tail linear)
__global__ __launch_bounds__(256) void k_fc(const unsigned short* __restrict__ h3,
                                            const unsigned short* __restrict__ fc1wb,
                                            const float* __restrict__ fc1b,
                                            const float* __restrict__ fc2w,
                                            const float* __restrict__ fc2b,
                                            float* __restrict__ out) {
  __shared__ __align__(16) unsigned short As[16 * FC1_KC];   // 50176 B
  const int bid = blockIdx.x;
  const int mtile = bid >> 1, nh = bid & 1;
  const int t = threadIdx.x, lane = t & 63, w = t >> 6;
  const int l15 = lane & 15, lk = lane >> 4;
  const int swz = l15 & 7;

  f32x4 acc = {0.f,0.f,0.f,0.f};
  const int nrow = nh*64 + w*16 + l15;    // fc1 output row this lane accumulates

  for (int kh = 0; kh < 8; ++kh) {
    if (kh) __syncthreads();              // prior MFMA reads of As complete
    const unsigned short* Ag = h3 + (size_t)(mtile*16)*12544 + kh*FC1_KC;
    #pragma unroll
    for (int rr = 0; rr < 4; ++rr) {
      const int r = w*4 + rr;
      const int f = r & 7;
      const unsigned short* rowg = Ag + (size_t)r*12544 + ((lane ^ f) * 8);
      #pragma unroll
      for (int p = 0; p < 3; ++p) {
        __builtin_amdgcn_global_load_lds(
            (const __attribute__((address_space(1))) unsigned int*)(rowg + p*512),
            (__attribute__((address_space(3))) unsigned int*)&As[r*FC1_KC + p*512],
            16, 0, 0);
      }
    }
    {
      const int r = t >> 4, o = (t & 15) * 2;
      *(unsigned int*)&As[r*FC1_KC + 1536 + o] =
          *(const unsigned int*)(Ag + (size_t)r*12544 + 1536 + o);
    }
    __syncthreads();

    const unsigned short* bp = fc1wb + (size_t)nrow*12544 + kh*FC1_KC + lk*8;
    #pragma unroll 7
    for (int ks = 0; ks < 49; ++ks) {
      const int b = ks*4 + lk;
      const int s = (ks < 48) ? (b ^ swz) : b;
      bf16x8 a  = *(const bf16x8*)&As[l15*FC1_KC + s*8];
      bf16x8 wv = *(const bf16x8*)(bp + ks*32);
      acc = __builtin_amdgcn_mfma_f32_16x16x32_bf16(a, wv, acc, 0, 0, 0);
    }
  }
  __syncthreads();                        // As reads done; reuse as hs
  float* hs = (float*)As;                 // [16][68]
  {
    const float bb = fc1b[nrow];
    #pragma unroll
    for (int jj = 0; jj < 4; ++jj) {
      const int r = lk*4 + jj;            // batch row within tile
      hs[r*68 + w*16 + l15] = fmaxf(acc[jj] + bb, 0.f);
    }
  }
  __syncthreads();
  if (t < 160) {
    const int bb = t / 10, n = t - (t/10)*10;
    float a2 = (nh == 0) ? fc2b[n] : 0.f;
    const float* wr = fc2w + n*128 + nh*64;
    const float* hr = hs + bb*68;
    #pragma unroll 8
    for (int k = 0; k < 64; ++k) a2 = fmaf(hr[k], wr[k], a2);
    atomicAdd(&out[(mtile*16 + bb)*10 + n], a2);
  }
}

extern "C" void kernel_launch(void* const* d_in, const int* in_sizes, int n_in,
                              void* d_out, int out_size, void* d_ws, size_t ws_size,
                              hipStream_t stream) {
  const float* x    = (const float*)d_in[0];
  const float* w1   = (const float*)d_in[1];
  const float* p1   = (const float*)d_in[2];
  const float* p2   = (const float*)d_in[3];
  const float* b1   = (const float*)d_in[4];
  const float* w2   = (const float*)d_in[5];
  const float* b2   = (const float*)d_in[6];
  const float* fc1w = (const float*)d_in[7];
  const float* fc1b = (const float*)d_in[8];
  const float* fc2w = (const float*)d_in[9];
  const float* fc2b = (const float*)d_in[10];

  // ws layout (bytes):
  //        0: k1b bf16[32][32]           (2048)
  //     4096: w2b bf16[9][64][32]        (36864)
  //    40960: fc1wb bf16[128][12544]     (3211264)
  //  3252224: h3 bf16[2048][64][14][14]  (51380224)  -> total 54632448
  if (ws_size < 54632448u) return;
  char* ws = (char*)d_ws;
  unsigned short* k1b  = (unsigned short*)(ws + 0);
  unsigned short* w2b  = (unsigned short*)(ws + 4096);
  unsigned short* fc1wb= (unsigned short*)(ws + 40960);
  unsigned short* h3   = (unsigned short*)(ws + 3252224);

  hipMemsetAsync(d_out, 0, (size_t)out_size * sizeof(float), stream);
  k_prep<<<(401408 + 18432 + 1024 + 255) / 256, 256, 0, stream>>>(
      w2, fc1w, w1, p1, p2, w2b, fc1wb, k1b);
  k_conv<<<NB, 256, 0, stream>>>(x, k1b, b1, w2b, b2, h3);
  k_fc<<<256, 256, 0, stream>>>(h3, fc1wb, fc1b, fc2w, fc2b, (float*)d_out);
}

// Round 6
// 147.595 us; speedup vs baseline: 1.1743x; 1.1743x over previous
//
#include <hip/hip_runtime.h>
#include <hip/hip_bf16.h>

typedef __attribute__((ext_vector_type(8))) short bf16x8;
typedef __attribute__((ext_vector_type(4))) float f32x4;
typedef __attribute__((ext_vector_type(4))) unsigned int u32x4;
typedef __attribute__((ext_vector_type(2))) unsigned int u32x2;

#define NB 2048
#define FC1_KC 1568   // K per kh-chunk (12544/8)

static __device__ __forceinline__ unsigned short f2bf(float f) {
  unsigned int u = __builtin_bit_cast(unsigned int, f);
  u += 0x7fffu + ((u >> 16) & 1u);   // RNE
  return (unsigned short)(u >> 16);
}
// HW packed f32->bf16 (RNE), two values into one dword
static __device__ __forceinline__ unsigned int cvtpk(float lo, float hi) {
  unsigned int r;
  asm("v_cvt_pk_bf16_f32 %0, %1, %2" : "=v"(r) : "v"(lo), "v"(hi));
  return r;
}

// ---------------- weight prep (single pass, vectorized fc1w) ----------------
__global__ __launch_bounds__(256) void k_prep(
    const float* __restrict__ w2, const float* __restrict__ fc1w,
    const float* __restrict__ w1, const float* __restrict__ p1,
    const float* __restrict__ p2,
    unsigned short* __restrict__ w2b, unsigned short* __restrict__ fc1wb,
    unsigned short* __restrict__ k1b) {
  const int gid = blockIdx.x * blockDim.x + threadIdx.x;
  if (gid < 401408) {
    f32x4 v = *(const f32x4*)&fc1w[gid*4];
    u32x2 r = { cvtpk(v[0], v[1]), cvtpk(v[2], v[3]) };
    *(u32x2*)&fc1wb[gid*4] = r;
  } else if (gid < 401408 + 18432) {
    int i = gid - 401408;
    int cin = i & 31;
    int cout = (i >> 5) & 63;
    int kk = i >> 11;          // 0..8
    int ky = kk / 3, kx = kk % 3;
    w2b[i] = f2bf(w2[((cout*32 + cin)*3 + ky)*3 + kx]);
  } else if (gid < 401408 + 18432 + 1024) {
    int t = gid - (401408 + 18432);  // 0..1023
    int o = t >> 5, tap = t & 31;
    unsigned short r = 0;
    if (tap < 25) {
      int a = tap / 5, bcol = tap % 5;
      float acc = 0.f;
      for (int k = 0; k < 26; ++k) {
        float q1 = p1[o*26 + k] + 2.0f;
        float q2 = p2[o*26 + k] + 2.0f;
        float f1 = floorf(q1), f2 = floorf(q2);
        int idx1 = (int)f1 + ((q1 - f1) >= 0.5f ? 1 : 0);
        int idx2 = (int)f2 + ((q2 - f2) >= 0.5f ? 1 : 0);
        if (idx1 == a && idx2 == bcol) acc += w1[o*26 + k];
      }
      r = f2bf(acc);
    }
    k1b[t] = r;
  }
}

// ---------------- fused conv1(MFMA)+relu -> conv2(MFMA)+relu+maxpool ----------------
// one block = one image; 3 blocks/CU (4 blocks/CU thrashes L2 write-combining:
// FETCH 3.4->38MB, WRITE 54->114MB measured — do NOT raise).
// h1s layout: pixel-major, 4x 16B cin-blocks per pixel, XOR-swizzled:
//   elem(pixel, cin) -> pixel*32 + ((cin>>3) ^ ((pixel>>1)&3))*8 + (cin&7)
__global__ __launch_bounds__(256, 3) void k_conv(
    const float* __restrict__ x, const unsigned short* __restrict__ k1b,
    const float* __restrict__ b1, const unsigned short* __restrict__ w2b,
    const float* __restrict__ b2, unsigned short* __restrict__ h3) {
  __shared__ __align__(16) float xs[32*36];              // padded input, stride 36
  __shared__ __align__(16) unsigned short h1s[16*32*32]; // one y-half, swizzled

  const int t = threadIdx.x;
  const int bimg = blockIdx.x;
  const int lane = t & 63;
  const int wid = t >> 6;
  const int l15 = lane & 15;
  const int lk = lane >> 4;

  // ---- stage x into xs (zero border) ----
  for (int i = t; i < 1152; i += 256) {
    int iy = i / 36, ix = i - iy*36;
    float v = 0.f;
    if (iy >= 2 && iy < 30 && ix >= 2 && ix < 30)
      v = x[bimg*784 + (iy-2)*28 + (ix-2)];
    xs[i] = v;
  }

  // ---- conv1 operands (registers) ----
  int off[8];                       // per-lane im2col tap offsets (taps>=25 clamp: A rows are 0 there)
  #pragma unroll
  for (int j = 0; j < 8; ++j) {
    int tp = lk*8 + j; tp = tp > 24 ? 24 : tp;
    int ky = tp / 5;
    off[j] = ky*36 + (tp - ky*5);
  }
  const bf16x8 k1a0 = *(const bf16x8*)&k1b[l15*32 + lk*8];
  const bf16x8 k1a1 = *(const bf16x8*)&k1b[(16 + l15)*32 + lk*8];
  float b1v[2][4];
  #pragma unroll
  for (int nt = 0; nt < 2; ++nt)
    #pragma unroll
    for (int r = 0; r < 4; ++r)
      b1v[nt][r] = b1[nt*16 + lk*4 + r];

  // ---- conv2 operands (registers) ----
  const int ntp = wid & 1;      // couts ntp*32 .. ntp*32+31
  const int tx  = wid >> 1;     // x half-tile (wave-uniform)
  bf16x8 bfr[2][9];
  #pragma unroll
  for (int nn = 0; nn < 2; ++nn)
    #pragma unroll
    for (int kk = 0; kk < 9; ++kk)
      bfr[nn][kk] = *(const bf16x8*)&w2b[(kk*64 + (ntp*2+nn)*16 + l15)*32 + lk*8];
  float b2v[2];
  b2v[0] = b2[ntp*32 + l15];
  b2v[1] = b2[ntp*32 + 16 + l15];
  int colOff[3];                // byte offsets into an h1s row (swizzle is row-independent)
  #pragma unroll
  for (int kx = 0; kx < 3; ++kx) {
    int xk = tx*16 + l15 + kx; xk = xk > 31 ? 31 : xk;   // clamped dummies read zero pads
    colOff[kx] = xk*64 + ((lk ^ ((xk >> 1) & 3)) << 4);
  }

  __syncthreads();

  for (int half = 0; half < 2; ++half) {
    if (half) __syncthreads();          // prev half's conv2 reads done

    // ---- zero pads for this half ----
    {
      u32x4* H = (u32x4*)h1s;
      u32x4 z = {0u,0u,0u,0u};
      const int zrow = half ? 15 : 0;   // full zero row (y'=0 / y'=29)
      if (t < 128) H[zrow*128 + t] = z;
      const int r0 = half ? 0 : 1;      // col pads on the 15 computed rows
      if (t < 240) {                    // 15 rows x 4 px x 4 chunks
        int rr = t >> 4, rem = t & 15;
        int pi = rem >> 2, sub = rem & 3;
        int px = pi == 0 ? 0 : 28 + pi; // x' in {0,29,30,31}
        H[((r0 + rr)*32 + px)*4 + sub] = z;
      }
    }

    // ---- conv1 via MFMA: A=k1[cout][tap], B=im2col[tap][pixel] ----
    const int ybase = half ? 13 : 0;
    for (int tid = wid; tid < 30; tid += 4) {
      const int ty = tid >> 1;                 // 0..14
      const int x0 = (tid & 1) << 4;
      const int yo = ybase + ty;               // conv output row
      const float* bp = &xs[yo*36 + x0 + l15];
      u32x4 bw;
      bw[0] = cvtpk(bp[off[0]], bp[off[1]]);
      bw[1] = cvtpk(bp[off[2]], bp[off[3]]);
      bw[2] = cvtpk(bp[off[4]], bp[off[5]]);
      bw[3] = cvtpk(bp[off[6]], bp[off[7]]);
      const bf16x8 bfrag = __builtin_bit_cast(bf16x8, bw);
      f32x4 d0 = {0.f,0.f,0.f,0.f}, d1 = {0.f,0.f,0.f,0.f};
      d0 = __builtin_amdgcn_mfma_f32_16x16x32_bf16(k1a0, bfrag, d0, 0, 0, 0);
      d1 = __builtin_amdgcn_mfma_f32_16x16x32_bf16(k1a1, bfrag, d1, 0, 0, 0);
      // D: col=l15=pixel, row=lk*4+reg=cout -> 4 consecutive couts per lane
      const int xo = x0 + l15;
      if (xo < 28) {
        const int ry = half ? (yo - 13) : (yo + 1);
        const int pix = ry*32 + xo + 1;
        const int swz = (pix >> 1) & 3;
        const int blkbase = (lk >> 1);
        unsigned int w0lo = cvtpk(fmaxf(d0[0] + b1v[0][0], 0.f), fmaxf(d0[1] + b1v[0][1], 0.f));
        unsigned int w0hi = cvtpk(fmaxf(d0[2] + b1v[0][2], 0.f), fmaxf(d0[3] + b1v[0][3], 0.f));
        unsigned int w1lo = cvtpk(fmaxf(d1[0] + b1v[1][0], 0.f), fmaxf(d1[1] + b1v[1][1], 0.f));
        unsigned int w1hi = cvtpk(fmaxf(d1[2] + b1v[1][2], 0.f), fmaxf(d1[3] + b1v[1][3], 0.f));
        char* base = (char*)h1s + pix*64 + (lk & 1)*8;
        *(u32x2*)(base + ((blkbase ^ swz) << 4))       = (u32x2){w0lo, w0hi};
        *(u32x2*)(base + (((2 + blkbase) ^ swz) << 4)) = (u32x2){w1lo, w1hi};
      }
    }
    __syncthreads();

    // ---- conv2 via MFMA ----
    const char* h1c = (const char*)h1s;
    for (int pyl = 0; pyl < 7; ++pyl) {
      const int py = half*7 + pyl;
      const int rbase = (2*py - (half ? 14 : 0)) * 2048;
      f32x4 acc[2][2];
      #pragma unroll
      for (int yi = 0; yi < 2; ++yi)
        #pragma unroll
        for (int nn = 0; nn < 2; ++nn) acc[yi][nn] = (f32x4){0.f,0.f,0.f,0.f};
      #pragma unroll
      for (int kx = 0; kx < 3; ++kx) {
        bf16x8 af[4];
        #pragma unroll
        for (int r = 0; r < 4; ++r)
          af[r] = *(const bf16x8*)(h1c + rbase + r*2048 + colOff[kx]);
        #pragma unroll
        for (int ky = 0; ky < 3; ++ky)
          #pragma unroll
          for (int yi = 0; yi < 2; ++yi) {
            acc[yi][0] = __builtin_amdgcn_mfma_f32_16x16x32_bf16(af[yi+ky], bfr[0][ky*3+kx], acc[yi][0], 0, 0, 0);
            acc[yi][1] = __builtin_amdgcn_mfma_f32_16x16x32_bf16(af[yi+ky], bfr[1][ky*3+kx], acc[yi][1], 0, 0, 0);
          }
      }
      // bias + relu + 2x2 maxpool in-register, write bf16
      float hm[2][2][2];   // [nn][yi][xpair]
      #pragma unroll
      for (int yi = 0; yi < 2; ++yi)
        #pragma unroll
        for (int nn = 0; nn < 2; ++nn) {
          float v0 = fmaxf(acc[yi][nn][0] + b2v[nn], 0.f);
          float v1 = fmaxf(acc[yi][nn][1] + b2v[nn], 0.f);
          float v2 = fmaxf(acc[yi][nn][2] + b2v[nn], 0.f);
          float v3 = fmaxf(acc[yi][nn][3] + b2v[nn], 0.f);
          hm[nn][yi][0] = fmaxf(v0, v1);
          hm[nn][yi][1] = fmaxf(v2, v3);
        }
      if (!(tx == 1 && lk == 3)) {                 // drop x>=28 dummy columns
        const int px0 = tx*8 + lk*2;
        #pragma unroll
        for (int nn = 0; nn < 2; ++nn) {
          float q0 = fmaxf(hm[nn][0][0], hm[nn][1][0]);
          float q1 = fmaxf(hm[nn][0][1], hm[nn][1][1]);
          const int c = ntp*32 + nn*16 + l15;
          *(unsigned int*)&h3[((size_t)(bimg*64 + c)*14 + py)*14 + px0] = cvtpk(q0, q1);
        }
      }
    }
  }
}

// ---------------- FC1 GEMM, no LDS: M=2048 N=128 K=12544, kh=8 ----------------
// A-frag reads straight from global (16x64B coalesced, L1-shared across the
// 4 waves that use the same 16 rows); no barriers, low VGPR -> deep occupancy.
__global__ __launch_bounds__(256) void k_fc1(const unsigned short* __restrict__ h3,
                                             const unsigned short* __restrict__ fc1wb,
                                             float* __restrict__ h4p) {
  const int bid = blockIdx.x;            // 128 mtiles x 8 kh
  const int mtile = bid >> 3, kh = bid & 7;
  const int t = threadIdx.x, lane = t & 63, w = t >> 6;
  const int l15 = lane & 15, lk = lane >> 4;

  const unsigned short* ap  = h3 + (size_t)(mtile*16 + l15)*12544 + kh*FC1_KC + lk*8;
  const unsigned short* b0p = fc1wb + (size_t)(w*32 + l15)*12544 + kh*FC1_KC + lk*8;
  const unsigned short* b1p = b0p + (size_t)16*12544;

  f32x4 acc0 = {0.f,0.f,0.f,0.f}, acc1 = {0.f,0.f,0.f,0.f};
  #pragma unroll 7
  for (int ks = 0; ks < 49; ++ks) {
    bf16x8 a  = *(const bf16x8*)(ap  + ks*32);
    bf16x8 w0 = *(const bf16x8*)(b0p + ks*32);
    bf16x8 w1 = *(const bf16x8*)(b1p + ks*32);
    acc0 = __builtin_amdgcn_mfma_f32_16x16x32_bf16(a, w0, acc0, 0, 0, 0);
    acc1 = __builtin_amdgcn_mfma_f32_16x16x32_bf16(a, w1, acc1, 0, 0, 0);
  }
  float* outp = h4p + (size_t)kh * NB * 128;
  const int n0 = w*32 + l15;
  #pragma unroll
  for (int jj = 0; jj < 4; ++jj) {
    const int bb = mtile*16 + lk*4 + jj;
    outp[bb*128 + n0]      = acc0[jj];
    outp[bb*128 + n0 + 16] = acc1[jj];
  }
}

// ---------------- K-partial reduce + bias + relu + FC2 ----------------
__global__ __launch_bounds__(256) void k_fc2(const float* __restrict__ h4p,
                                             const float* __restrict__ fc1b,
                                             const float* __restrict__ fc2w,
                                             const float* __restrict__ fc2b,
                                             float* __restrict__ out) {
  __shared__ float hs[8*129];
  const int blk = blockIdx.x;    // 256 blocks x 8 batches
  const int t = threadIdx.x;
  for (int i = t; i < 1024; i += 256) {
    const int base = blk*1024 + i;
    float v = 0.f;
    #pragma unroll
    for (int kh = 0; kh < 8; ++kh) v += h4p[base + kh*262144];
    v += fc1b[i & 127];
    hs[(i >> 7)*129 + (i & 127)] = fmaxf(v, 0.f);
  }
  __syncthreads();
  if (t < 80) {
    const int bb = t / 10, n = t - (t/10)*10;
    float acc = fc2b[n];
    const float* wr = fc2w + n*128;
    const float* hr = hs + bb*129;
    #pragma unroll 8
    for (int k = 0; k < 128; ++k) acc = fmaf(hr[k], wr[k], acc);
    out[(blk*8 + bb)*10 + n] = acc;
  }
}

extern "C" void kernel_launch(void* const* d_in, const int* in_sizes, int n_in,
                              void* d_out, int out_size, void* d_ws, size_t ws_size,
                              hipStream_t stream) {
  const float* x    = (const float*)d_in[0];
  const float* w1   = (const float*)d_in[1];
  const float* p1   = (const float*)d_in[2];
  const float* p2   = (const float*)d_in[3];
  const float* b1   = (const float*)d_in[4];
  const float* w2   = (const float*)d_in[5];
  const float* b2   = (const float*)d_in[6];
  const float* fc1w = (const float*)d_in[7];
  const float* fc1b = (const float*)d_in[8];
  const float* fc2w = (const float*)d_in[9];
  const float* fc2b = (const float*)d_in[10];

  // ws layout (bytes):
  //        0: k1b bf16[32][32]           (2048)
  //     4096: w2b bf16[9][64][32]        (36864)
  //    40960: fc1wb bf16[128][12544]     (3211264)
  //  3252224: h3 bf16[2048][64][14][14]  (51380224)
  // 54632448: h4p f32[8][2048][128]      (8388608)  -> total 63021056
  if (ws_size < 63021056u) return;
  char* ws = (char*)d_ws;
  unsigned short* k1b  = (unsigned short*)(ws + 0);
  unsigned short* w2b  = (unsigned short*)(ws + 4096);
  unsigned short* fc1wb= (unsigned short*)(ws + 40960);
  unsigned short* h3   = (unsigned short*)(ws + 3252224);
  float* h4p           = (float*)(ws + 54632448);

  k_prep<<<(401408 + 18432 + 1024 + 255) / 256, 256, 0, stream>>>(
      w2, fc1w, w1, p1, p2, w2b, fc1wb, k1b);
  k_conv<<<NB, 256, 0, stream>>>(x, k1b, b1, w2b, b2, h3);
  k_fc1<<<1024, 256, 0, stream>>>(h3, fc1wb, h4p);
  k_fc2<<<256, 256, 0, stream>>>(h4p, fc1b, fc2w, fc2b, (float*)d_out);
}

// Round 7
// 116.424 us; speedup vs baseline: 1.4887x; 1.2677x over previous
//
#include <hip/hip_runtime.h>
#include <hip/hip_bf16.h>

typedef __attribute__((ext_vector_type(8))) short bf16x8;
typedef __attribute__((ext_vector_type(4))) float f32x4;
typedef __attribute__((ext_vector_type(4))) unsigned int u32x4;
typedef __attribute__((ext_vector_type(2))) unsigned int u32x2;

#define NB 2048

static __device__ __forceinline__ unsigned short f2bf(float f) {
  unsigned int u = __builtin_bit_cast(unsigned int, f);
  u += 0x7fffu + ((u >> 16) & 1u);   // RNE
  return (unsigned short)(u >> 16);
}
// HW packed f32->bf16 (RNE), two values into one dword
static __device__ __forceinline__ unsigned int cvtpk(float lo, float hi) {
  unsigned int r;
  asm("v_cvt_pk_bf16_f32 %0, %1, %2" : "=v"(r) : "v"(lo), "v"(hi));
  return r;
}

// ---------------- weight prep (single pass) ----------------
// fc1wbF fragment layout: idx = q*4096 + n*32 + kw   (q=k>>5, kw=k&31, k=0..12543)
//   -> a wave's B-fragment (16 n x 32 k) is 1KB contiguous.
__global__ __launch_bounds__(256) void k_prep(
    const float* __restrict__ w2, const float* __restrict__ fc1w,
    const float* __restrict__ w1, const float* __restrict__ p1,
    const float* __restrict__ p2,
    unsigned short* __restrict__ w2b, unsigned short* __restrict__ fc1wb,
    unsigned short* __restrict__ k1b) {
  const int gid = blockIdx.x * blockDim.x + threadIdx.x;
  if (gid < 401408) {
    const int j0 = gid * 4;               // 4 consecutive kw, same (q, n)
    const int kw = j0 & 31;
    const int n  = (j0 >> 5) & 127;
    const int q  = j0 >> 12;
    f32x4 v = *(const f32x4*)&fc1w[n*12544 + q*32 + kw];
    u32x2 r = { cvtpk(v[0], v[1]), cvtpk(v[2], v[3]) };
    *(u32x2*)&fc1wb[j0] = r;
  } else if (gid < 401408 + 18432) {
    int i = gid - 401408;
    int cin = i & 31;
    int cout = (i >> 5) & 63;
    int kk = i >> 11;          // 0..8
    int ky = kk / 3, kx = kk % 3;
    w2b[i] = f2bf(w2[((cout*32 + cin)*3 + ky)*3 + kx]);
  } else if (gid < 401408 + 18432 + 1024) {
    int t = gid - (401408 + 18432);  // 0..1023
    int o = t >> 5, tap = t & 31;
    unsigned short r = 0;
    if (tap < 25) {
      int a = tap / 5, bcol = tap % 5;
      float acc = 0.f;
      for (int k = 0; k < 26; ++k) {
        float q1 = p1[o*26 + k] + 2.0f;
        float q2 = p2[o*26 + k] + 2.0f;
        float f1 = floorf(q1), f2 = floorf(q2);
        int idx1 = (int)f1 + ((q1 - f1) >= 0.5f ? 1 : 0);
        int idx2 = (int)f2 + ((q2 - f2) >= 0.5f ? 1 : 0);
        if (idx1 == a && idx2 == bcol) acc += w1[o*26 + k];
      }
      r = f2bf(acc);
    }
    k1b[t] = r;
  }
}

// ---------------- fused conv1(MFMA)+relu -> conv2(MFMA)+relu+maxpool ----------------
// one block = one image; 3 blocks/CU (4 blocks/CU thrashes L2 write-combining —
// measured FETCH 3.4->38MB, WRITE 54->114MB; do NOT raise).
// h1s layout: pixel-major, 4x 16B cin-blocks per pixel, XOR-swizzled.
// h3F OUTPUT fragment layout: idx = mtile*200704 + ks*512 + mi*32 + kw
//   (b = mtile*16+mi; k = c*196+py*14+px; ks=k>>5, kw=k&31)
__global__ __launch_bounds__(256, 3) void k_conv(
    const float* __restrict__ x, const unsigned short* __restrict__ k1b,
    const float* __restrict__ b1, const unsigned short* __restrict__ w2b,
    const float* __restrict__ b2, unsigned short* __restrict__ h3) {
  __shared__ __align__(16) float xs[32*36];              // padded input, stride 36
  __shared__ __align__(16) unsigned short h1s[16*32*32]; // one y-half, swizzled

  const int t = threadIdx.x;
  const int bimg = blockIdx.x;
  const int lane = t & 63;
  const int wid = t >> 6;
  const int l15 = lane & 15;
  const int lk = lane >> 4;

  // ---- stage x into xs (zero border) ----
  for (int i = t; i < 1152; i += 256) {
    int iy = i / 36, ix = i - iy*36;
    float v = 0.f;
    if (iy >= 2 && iy < 30 && ix >= 2 && ix < 30)
      v = x[bimg*784 + (iy-2)*28 + (ix-2)];
    xs[i] = v;
  }

  // ---- conv1 operands (registers) ----
  int off[8];                       // per-lane im2col tap offsets (taps>=25 clamp: A rows are 0 there)
  #pragma unroll
  for (int j = 0; j < 8; ++j) {
    int tp = lk*8 + j; tp = tp > 24 ? 24 : tp;
    int ky = tp / 5;
    off[j] = ky*36 + (tp - ky*5);
  }
  const bf16x8 k1a0 = *(const bf16x8*)&k1b[l15*32 + lk*8];
  const bf16x8 k1a1 = *(const bf16x8*)&k1b[(16 + l15)*32 + lk*8];
  f32x4 b1i0, b1i1;                 // MFMA acc-init with bias (row = cout = lk*4+reg)
  #pragma unroll
  for (int r = 0; r < 4; ++r) {
    b1i0[r] = b1[lk*4 + r];
    b1i1[r] = b1[16 + lk*4 + r];
  }

  // ---- conv2 operands (registers) ----
  const int ntp = wid & 1;      // couts ntp*32 .. ntp*32+31
  const int tx  = wid >> 1;     // x half-tile (wave-uniform)
  bf16x8 bfr[2][9];
  #pragma unroll
  for (int nn = 0; nn < 2; ++nn)
    #pragma unroll
    for (int kk = 0; kk < 9; ++kk)
      bfr[nn][kk] = *(const bf16x8*)&w2b[(kk*64 + (ntp*2+nn)*16 + l15)*32 + lk*8];
  f32x4 b2i[2];                 // acc-init (col = cout = l15, same across rows)
  #pragma unroll
  for (int nn = 0; nn < 2; ++nn) {
    float bb = b2[ntp*32 + nn*16 + l15];
    b2i[nn] = (f32x4){bb, bb, bb, bb};
  }
  int colOff[3];                // byte offsets into an h1s row (swizzle is row-independent)
  #pragma unroll
  for (int kx = 0; kx < 3; ++kx) {
    int xk = tx*16 + l15 + kx; xk = xk > 31 ? 31 : xk;   // clamped dummies read zero pads
    colOff[kx] = xk*64 + ((lk ^ ((xk >> 1) & 3)) << 4);
  }

  const int mtile = bimg >> 4, mi = bimg & 15;
  unsigned short* h3m = h3 + (size_t)mtile*200704 + mi*32;

  __syncthreads();

  for (int half = 0; half < 2; ++half) {
    if (half) __syncthreads();          // prev half's conv2 reads done

    // ---- zero pads for this half ----
    {
      u32x4* H = (u32x4*)h1s;
      u32x4 z = {0u,0u,0u,0u};
      const int zrow = half ? 15 : 0;   // full zero row (y'=0 / y'=29)
      if (t < 128) H[zrow*128 + t] = z;
      const int r0 = half ? 0 : 1;      // col pads on the 15 computed rows
      if (t < 240) {                    // 15 rows x 4 px x 4 chunks
        int rr = t >> 4, rem = t & 15;
        int pi = rem >> 2, sub = rem & 3;
        int px = pi == 0 ? 0 : 28 + pi; // x' in {0,29,30,31}
        H[((r0 + rr)*32 + px)*4 + sub] = z;
      }
    }

    // ---- conv1 via MFMA: A=k1[cout][tap], B=im2col[tap][pixel] ----
    const int ybase = half ? 13 : 0;
    for (int tid = wid; tid < 30; tid += 4) {
      const int ty = tid >> 1;                 // 0..14
      const int x0 = (tid & 1) << 4;
      const int yo = ybase + ty;               // conv output row
      const float* bp = &xs[yo*36 + x0 + l15];
      u32x4 bw;
      bw[0] = cvtpk(bp[off[0]], bp[off[1]]);
      bw[1] = cvtpk(bp[off[2]], bp[off[3]]);
      bw[2] = cvtpk(bp[off[4]], bp[off[5]]);
      bw[3] = cvtpk(bp[off[6]], bp[off[7]]);
      const bf16x8 bfrag = __builtin_bit_cast(bf16x8, bw);
      f32x4 d0 = b1i0, d1 = b1i1;
      d0 = __builtin_amdgcn_mfma_f32_16x16x32_bf16(k1a0, bfrag, d0, 0, 0, 0);
      d1 = __builtin_amdgcn_mfma_f32_16x16x32_bf16(k1a1, bfrag, d1, 0, 0, 0);
      // D: col=l15=pixel, row=lk*4+reg=cout -> 4 consecutive couts per lane
      const int xo = x0 + l15;
      if (xo < 28) {
        const int ry = half ? (yo - 13) : (yo + 1);
        const int pix = ry*32 + xo + 1;
        const int swz = (pix >> 1) & 3;
        const int blkbase = (lk >> 1);
        unsigned int w0lo = cvtpk(fmaxf(d0[0], 0.f), fmaxf(d0[1], 0.f));
        unsigned int w0hi = cvtpk(fmaxf(d0[2], 0.f), fmaxf(d0[3], 0.f));
        unsigned int w1lo = cvtpk(fmaxf(d1[0], 0.f), fmaxf(d1[1], 0.f));
        unsigned int w1hi = cvtpk(fmaxf(d1[2], 0.f), fmaxf(d1[3], 0.f));
        char* base = (char*)h1s + pix*64 + (lk & 1)*8;
        *(u32x2*)(base + ((blkbase ^ swz) << 4))       = (u32x2){w0lo, w0hi};
        *(u32x2*)(base + (((2 + blkbase) ^ swz) << 4)) = (u32x2){w1lo, w1hi};
      }
    }
    __syncthreads();

    // ---- conv2 via MFMA ----
    const char* h1c = (const char*)h1s;
    for (int pyl = 0; pyl < 7; ++pyl) {
      const int py = half*7 + pyl;
      const int rbase = (2*py - (half ? 14 : 0)) * 2048;
      f32x4 acc[2][2];
      #pragma unroll
      for (int yi = 0; yi < 2; ++yi)
        #pragma unroll
        for (int nn = 0; nn < 2; ++nn) acc[yi][nn] = b2i[nn];
      #pragma unroll
      for (int kx = 0; kx < 3; ++kx) {
        bf16x8 af[4];
        #pragma unroll
        for (int r = 0; r < 4; ++r)
          af[r] = *(const bf16x8*)(h1c + rbase + r*2048 + colOff[kx]);
        #pragma unroll
        for (int ky = 0; ky < 3; ++ky)
          #pragma unroll
          for (int yi = 0; yi < 2; ++yi) {
            acc[yi][0] = __builtin_amdgcn_mfma_f32_16x16x32_bf16(af[yi+ky], bfr[0][ky*3+kx], acc[yi][0], 0, 0, 0);
            acc[yi][1] = __builtin_amdgcn_mfma_f32_16x16x32_bf16(af[yi+ky], bfr[1][ky*3+kx], acc[yi][1], 0, 0, 0);
          }
      }
      // relu + 2x2 maxpool in-register, write bf16 to fragment-layout h3
      float hm[2][2][2];   // [nn][yi][xpair]
      #pragma unroll
      for (int yi = 0; yi < 2; ++yi)
        #pragma unroll
        for (int nn = 0; nn < 2; ++nn) {
          float v0 = fmaxf(acc[yi][nn][0], 0.f);
          float v1 = fmaxf(acc[yi][nn][1], 0.f);
          float v2 = fmaxf(acc[yi][nn][2], 0.f);
          float v3 = fmaxf(acc[yi][nn][3], 0.f);
          hm[nn][yi][0] = fmaxf(v0, v1);
          hm[nn][yi][1] = fmaxf(v2, v3);
        }
      if (!(tx == 1 && lk == 3)) {                 // drop x>=28 dummy columns
        const int px0 = tx*8 + lk*2;
        #pragma unroll
        for (int nn = 0; nn < 2; ++nn) {
          float q0 = fmaxf(hm[nn][0][0], hm[nn][1][0]);
          float q1 = fmaxf(hm[nn][0][1], hm[nn][1][1]);
          const int c = ntp*32 + nn*16 + l15;
          const int k0 = c*196 + py*14 + px0;      // even
          *(unsigned int*)&h3m[(k0 >> 5)*512 + (k0 & 31)] = cvtpk(q0, q1);
        }
      }
    }
  }
}

// ---------------- FC1 GEMM, fragment-layout operands, no LDS ----------------
// Every A/B fragment load = contiguous coalesced 1KB wave-load.
__global__ __launch_bounds__(256) void k_fc1(const unsigned short* __restrict__ h3,
                                             const unsigned short* __restrict__ fc1wb,
                                             float* __restrict__ h4p) {
  const int bid = blockIdx.x;            // 128 mtiles x 8 kh  (kh = XCD -> B L2-hot)
  const int mtile = bid >> 3, kh = bid & 7;
  const int t = threadIdx.x, lane = t & 63, w = t >> 6;
  const int l15 = lane & 15, lk = lane >> 4;
  const int lo = l15*32 + lk*8;          // fragment-internal offset (512 shorts)

  const unsigned short* ap  = h3    + (size_t)mtile*200704 + (size_t)(kh*49)*512 + lo;
  const unsigned short* b0p = fc1wb + (size_t)(kh*49)*4096 + (w*32)*32 + lo;

  f32x4 acc0 = {0.f,0.f,0.f,0.f}, acc1 = {0.f,0.f,0.f,0.f};
  #pragma unroll 7
  for (int ks = 0; ks < 49; ++ks) {
    bf16x8 a  = *(const bf16x8*)(ap  + ks*512);
    bf16x8 w0 = *(const bf16x8*)(b0p + ks*4096);
    bf16x8 w1 = *(const bf16x8*)(b0p + ks*4096 + 512);
    acc0 = __builtin_amdgcn_mfma_f32_16x16x32_bf16(a, w0, acc0, 0, 0, 0);
    acc1 = __builtin_amdgcn_mfma_f32_16x16x32_bf16(a, w1, acc1, 0, 0, 0);
  }
  float* outp = h4p + (size_t)kh * NB * 128;
  const int n0 = w*32 + l15;
  #pragma unroll
  for (int jj = 0; jj < 4; ++jj) {
    const int bb = mtile*16 + lk*4 + jj;
    outp[bb*128 + n0]      = acc0[jj];
    outp[bb*128 + n0 + 16] = acc1[jj];
  }
}

// ---------------- K-partial reduce + bias + relu + FC2 ----------------
__global__ __launch_bounds__(256) void k_fc2(const float* __restrict__ h4p,
                                             const float* __restrict__ fc1b,
                                             const float* __restrict__ fc2w,
                                             const float* __restrict__ fc2b,
                                             float* __restrict__ out) {
  __shared__ float hs[8*129];
  const int blk = blockIdx.x;    // 256 blocks x 8 batches
  const int t = threadIdx.x;
  for (int i = t; i < 1024; i += 256) {
    const int base = blk*1024 + i;
    float v = 0.f;
    #pragma unroll
    for (int kh = 0; kh < 8; ++kh) v += h4p[base + kh*262144];
    v += fc1b[i & 127];
    hs[(i >> 7)*129 + (i & 127)] = fmaxf(v, 0.f);
  }
  __syncthreads();
  if (t < 80) {
    const int bb = t / 10, n = t - (t/10)*10;
    float acc = fc2b[n];
    const float* wr = fc2w + n*128;
    const float* hr = hs + bb*129;
    #pragma unroll 8
    for (int k = 0; k < 128; ++k) acc = fmaf(hr[k], wr[k], acc);
    out[(blk*8 + bb)*10 + n] = acc;
  }
}

extern "C" void kernel_launch(void* const* d_in, const int* in_sizes, int n_in,
                              void* d_out, int out_size, void* d_ws, size_t ws_size,
                              hipStream_t stream) {
  const float* x    = (const float*)d_in[0];
  const float* w1   = (const float*)d_in[1];
  const float* p1   = (const float*)d_in[2];
  const float* p2   = (const float*)d_in[3];
  const float* b1   = (const float*)d_in[4];
  const float* w2   = (const float*)d_in[5];
  const float* b2   = (const float*)d_in[6];
  const float* fc1w = (const float*)d_in[7];
  const float* fc1b = (const float*)d_in[8];
  const float* fc2w = (const float*)d_in[9];
  const float* fc2b = (const float*)d_in[10];

  // ws layout (bytes):
  //        0: k1b bf16[32][32]             (2048)
  //     4096: w2b bf16[9][64][32]          (36864)
  //    40960: fc1wbF bf16[392][128][32]    (3211264)
  //  3252224: h3F bf16[128][392][16][32]   (51380224)
  // 54632448: h4p f32[8][2048][128]        (8388608)  -> total 63021056
  if (ws_size < 63021056u) return;
  char* ws = (char*)d_ws;
  unsigned short* k1b  = (unsigned short*)(ws + 0);
  unsigned short* w2b  = (unsigned short*)(ws + 4096);
  unsigned short* fc1wb= (unsigned short*)(ws + 40960);
  unsigned short* h3   = (unsigned short*)(ws + 3252224);
  float* h4p           = (float*)(ws + 54632448);

  k_prep<<<(401408 + 18432 + 1024 + 255) / 256, 256, 0, stream>>>(
      w2, fc1w, w1, p1, p2, w2b, fc1wb, k1b);
  k_conv<<<NB, 256, 0, stream>>>(x, k1b, b1, w2b, b2, h3);
  k_fc1<<<1024, 256, 0, stream>>>(h3, fc1wb, h4p);
  k_fc2<<<256, 256, 0, stream>>>(h4p, fc1b, fc2w, fc2b, (float*)d_out);
}

// Round 8
// 116.008 us; speedup vs baseline: 1.4940x; 1.0036x over previous
//
#include <hip/hip_runtime.h>
#include <hip/hip_bf16.h>

typedef __attribute__((ext_vector_type(8))) short bf16x8;
typedef __attribute__((ext_vector_type(4))) float f32x4;
typedef __attribute__((ext_vector_type(4))) unsigned int u32x4;
typedef __attribute__((ext_vector_type(2))) unsigned int u32x2;

#define NB 2048

static __device__ __forceinline__ unsigned short f2bf(float f) {
  unsigned int u = __builtin_bit_cast(unsigned int, f);
  u += 0x7fffu + ((u >> 16) & 1u);   // RNE
  return (unsigned short)(u >> 16);
}
// HW packed f32->bf16 (RNE), two values into one dword
static __device__ __forceinline__ unsigned int cvtpk(float lo, float hi) {
  unsigned int r;
  asm("v_cvt_pk_bf16_f32 %0, %1, %2" : "=v"(r) : "v"(lo), "v"(hi));
  return r;
}

// ---------------- weight prep (single pass) ----------------
// fc1wbF fragment layout: idx = q*4096 + n*32 + kw   (q=k>>5, kw=k&31)
__global__ __launch_bounds__(256) void k_prep(
    const float* __restrict__ w2, const float* __restrict__ fc1w,
    const float* __restrict__ w1, const float* __restrict__ p1,
    const float* __restrict__ p2,
    unsigned short* __restrict__ w2b, unsigned short* __restrict__ fc1wb,
    unsigned short* __restrict__ k1b) {
  const int gid = blockIdx.x * blockDim.x + threadIdx.x;
  if (gid < 401408) {
    const int j0 = gid * 4;               // 4 consecutive kw, same (q, n)
    const int kw = j0 & 31;
    const int n  = (j0 >> 5) & 127;
    const int q  = j0 >> 12;
    f32x4 v = *(const f32x4*)&fc1w[n*12544 + q*32 + kw];
    u32x2 r = { cvtpk(v[0], v[1]), cvtpk(v[2], v[3]) };
    *(u32x2*)&fc1wb[j0] = r;
  } else if (gid < 401408 + 18432) {
    int i = gid - 401408;
    int cin = i & 31;
    int cout = (i >> 5) & 63;
    int kk = i >> 11;          // 0..8
    int ky = kk / 3, kx = kk % 3;
    w2b[i] = f2bf(w2[((cout*32 + cin)*3 + ky)*3 + kx]);
  } else if (gid < 401408 + 18432 + 1024) {
    int t = gid - (401408 + 18432);  // 0..1023
    int o = t >> 5, tap = t & 31;
    unsigned short r = 0;
    if (tap < 25) {
      int a = tap / 5, bcol = tap % 5;
      float acc = 0.f;
      for (int k = 0; k < 26; ++k) {
        float q1 = p1[o*26 + k] + 2.0f;
        float q2 = p2[o*26 + k] + 2.0f;
        float f1 = floorf(q1), f2 = floorf(q2);
        int idx1 = (int)f1 + ((q1 - f1) >= 0.5f ? 1 : 0);
        int idx2 = (int)f2 + ((q2 - f2) >= 0.5f ? 1 : 0);
        if (idx1 == a && idx2 == bcol) acc += w1[o*26 + k];
      }
      r = f2bf(acc);
    }
    k1b[t] = r;
  }
}

// ---------------- fused conv1(MFMA)+relu -> conv2(MFMA)+relu+maxpool ----------------
// one block = one image; 3 blocks/CU (4 blocks/CU thrashes L2 write-combining —
// measured FETCH 3.4->38MB, WRITE 54->114MB; do NOT raise).
// h1s layout: pixel-major, 4x 16B cin-blocks per pixel, XOR-swizzled.
// h3F OUTPUT fragment layout: idx = mtile*200704 + ks*512 + mi*32 + kw
__global__ __launch_bounds__(256, 3) void k_conv(
    const float* __restrict__ x, const unsigned short* __restrict__ k1b,
    const float* __restrict__ b1, const unsigned short* __restrict__ w2b,
    const float* __restrict__ b2, unsigned short* __restrict__ h3) {
  __shared__ __align__(16) float xs[32*36];              // padded input, stride 36
  __shared__ __align__(16) unsigned short h1s[16*32*32]; // one y-half, swizzled

  const int t = threadIdx.x;
  const int bimg = blockIdx.x;
  const int lane = t & 63;
  const int wid = t >> 6;
  const int l15 = lane & 15;
  const int lk = lane >> 4;

  // ---- stage x into xs (zero border) ----
  for (int i = t; i < 1152; i += 256) {
    int iy = i / 36, ix = i - iy*36;
    float v = 0.f;
    if (iy >= 2 && iy < 30 && ix >= 2 && ix < 30)
      v = x[bimg*784 + (iy-2)*28 + (ix-2)];
    xs[i] = v;
  }

  // ---- conv1 operands (registers) ----
  int off[8];                       // per-lane im2col tap offsets (taps>=25 clamp: A rows are 0 there)
  #pragma unroll
  for (int j = 0; j < 8; ++j) {
    int tp = lk*8 + j; tp = tp > 24 ? 24 : tp;
    int ky = tp / 5;
    off[j] = ky*36 + (tp - ky*5);
  }
  const bf16x8 k1a0 = *(const bf16x8*)&k1b[l15*32 + lk*8];
  const bf16x8 k1a1 = *(const bf16x8*)&k1b[(16 + l15)*32 + lk*8];
  f32x4 b1i0, b1i1;                 // MFMA acc-init with bias (row = cout = lk*4+reg)
  #pragma unroll
  for (int r = 0; r < 4; ++r) {
    b1i0[r] = b1[lk*4 + r];
    b1i1[r] = b1[16 + lk*4 + r];
  }

  // ---- conv2 operands (registers) ----
  const int ntp = wid & 1;      // couts ntp*32 .. ntp*32+31
  const int tx  = wid >> 1;     // x half-tile (wave-uniform)
  bf16x8 bfr[2][9];
  #pragma unroll
  for (int nn = 0; nn < 2; ++nn)
    #pragma unroll
    for (int kk = 0; kk < 9; ++kk)
      bfr[nn][kk] = *(const bf16x8*)&w2b[(kk*64 + (ntp*2+nn)*16 + l15)*32 + lk*8];
  f32x4 b2i[2];                 // acc-init (col = cout = l15, same across rows)
  #pragma unroll
  for (int nn = 0; nn < 2; ++nn) {
    float bb = b2[ntp*32 + nn*16 + l15];
    b2i[nn] = (f32x4){bb, bb, bb, bb};
  }
  int colOff[3];                // byte offsets into an h1s row (swizzle is row-independent)
  #pragma unroll
  for (int kx = 0; kx < 3; ++kx) {
    int xk = tx*16 + l15 + kx; xk = xk > 31 ? 31 : xk;   // clamped dummies read zero pads
    colOff[kx] = xk*64 + ((lk ^ ((xk >> 1) & 3)) << 4);
  }

  const int mtile = bimg >> 4, mi = bimg & 15;
  unsigned short* h3m = h3 + (size_t)mtile*200704 + mi*32;

  __syncthreads();

  for (int half = 0; half < 2; ++half) {
    if (half) __syncthreads();          // prev half's conv2 reads done

    // ---- zero pads for this half ----
    {
      u32x4* H = (u32x4*)h1s;
      u32x4 z = {0u,0u,0u,0u};
      const int zrow = half ? 15 : 0;   // full zero row (y'=0 / y'=29)
      if (t < 128) H[zrow*128 + t] = z;
      const int r0 = half ? 0 : 1;      // col pads on the 15 computed rows
      if (t < 240) {                    // 15 rows x 4 px x 4 chunks
        int rr = t >> 4, rem = t & 15;
        int pi = rem >> 2, sub = rem & 3;
        int px = pi == 0 ? 0 : 28 + pi; // x' in {0,29,30,31}
        H[((r0 + rr)*32 + px)*4 + sub] = z;
      }
    }

    // ---- conv1 via MFMA: A=k1[cout][tap], B=im2col[tap][pixel] ----
    const int ybase = half ? 13 : 0;
    for (int tid = wid; tid < 30; tid += 4) {
      const int ty = tid >> 1;                 // 0..14
      const int x0 = (tid & 1) << 4;
      const int yo = ybase + ty;               // conv output row
      const float* bp = &xs[yo*36 + x0 + l15];
      u32x4 bw;
      bw[0] = cvtpk(bp[off[0]], bp[off[1]]);
      bw[1] = cvtpk(bp[off[2]], bp[off[3]]);
      bw[2] = cvtpk(bp[off[4]], bp[off[5]]);
      bw[3] = cvtpk(bp[off[6]], bp[off[7]]);
      const bf16x8 bfrag = __builtin_bit_cast(bf16x8, bw);
      f32x4 d0 = b1i0, d1 = b1i1;
      d0 = __builtin_amdgcn_mfma_f32_16x16x32_bf16(k1a0, bfrag, d0, 0, 0, 0);
      d1 = __builtin_amdgcn_mfma_f32_16x16x32_bf16(k1a1, bfrag, d1, 0, 0, 0);
      // D: col=l15=pixel, row=lk*4+reg=cout -> 4 consecutive couts per lane
      const int xo = x0 + l15;
      if (xo < 28) {
        const int ry = half ? (yo - 13) : (yo + 1);
        const int pix = ry*32 + xo + 1;
        const int swz = (pix >> 1) & 3;
        const int blkbase = (lk >> 1);
        unsigned int w0lo = cvtpk(fmaxf(d0[0], 0.f), fmaxf(d0[1], 0.f));
        unsigned int w0hi = cvtpk(fmaxf(d0[2], 0.f), fmaxf(d0[3], 0.f));
        unsigned int w1lo = cvtpk(fmaxf(d1[0], 0.f), fmaxf(d1[1], 0.f));
        unsigned int w1hi = cvtpk(fmaxf(d1[2], 0.f), fmaxf(d1[3], 0.f));
        char* base = (char*)h1s + pix*64 + (lk & 1)*8;
        *(u32x2*)(base + ((blkbase ^ swz) << 4))       = (u32x2){w0lo, w0hi};
        *(u32x2*)(base + (((2 + blkbase) ^ swz) << 4)) = (u32x2){w1lo, w1hi};
      }
    }
    __syncthreads();

    // ---- conv2 via MFMA, rolling 2-row register cache (halves LDS reads) ----
    const char* h1c = (const char*)h1s;
    bf16x8 c0[3], c1[3];               // cached rows 2*pyl+0, 2*pyl+1
    #pragma unroll
    for (int kx = 0; kx < 3; ++kx) {
      c0[kx] = *(const bf16x8*)(h1c + 0*2048 + colOff[kx]);
      c1[kx] = *(const bf16x8*)(h1c + 1*2048 + colOff[kx]);
    }
    #pragma unroll
    for (int pyl = 0; pyl < 7; ++pyl) {
      const int py = half*7 + pyl;
      const int rbase = pyl*2*2048;
      bf16x8 r2[3], r3[3];
      #pragma unroll
      for (int kx = 0; kx < 3; ++kx) {
        r2[kx] = *(const bf16x8*)(h1c + rbase + 2*2048 + colOff[kx]);
        r3[kx] = *(const bf16x8*)(h1c + rbase + 3*2048 + colOff[kx]);
      }
#define AROW(r, kx) ((r)==0 ? c0[kx] : (r)==1 ? c1[kx] : (r)==2 ? r2[kx] : r3[kx])
      f32x4 acc[2][2];
      #pragma unroll
      for (int yi = 0; yi < 2; ++yi)
        #pragma unroll
        for (int nn = 0; nn < 2; ++nn) acc[yi][nn] = b2i[nn];
      #pragma unroll
      for (int kx = 0; kx < 3; ++kx)
        #pragma unroll
        for (int ky = 0; ky < 3; ++ky)
          #pragma unroll
          for (int yi = 0; yi < 2; ++yi) {
            acc[yi][0] = __builtin_amdgcn_mfma_f32_16x16x32_bf16(AROW(yi+ky, kx), bfr[0][ky*3+kx], acc[yi][0], 0, 0, 0);
            acc[yi][1] = __builtin_amdgcn_mfma_f32_16x16x32_bf16(AROW(yi+ky, kx), bfr[1][ky*3+kx], acc[yi][1], 0, 0, 0);
          }
#undef AROW
      // relu + 2x2 maxpool in-register, write bf16 to fragment-layout h3
      float hm[2][2][2];   // [nn][yi][xpair]
      #pragma unroll
      for (int yi = 0; yi < 2; ++yi)
        #pragma unroll
        for (int nn = 0; nn < 2; ++nn) {
          float v0 = fmaxf(acc[yi][nn][0], 0.f);
          float v1 = fmaxf(acc[yi][nn][1], 0.f);
          float v2 = fmaxf(acc[yi][nn][2], 0.f);
          float v3 = fmaxf(acc[yi][nn][3], 0.f);
          hm[nn][yi][0] = fmaxf(v0, v1);
          hm[nn][yi][1] = fmaxf(v2, v3);
        }
      if (!(tx == 1 && lk == 3)) {                 // drop x>=28 dummy columns
        const int px0 = tx*8 + lk*2;
        #pragma unroll
        for (int nn = 0; nn < 2; ++nn) {
          float q0 = fmaxf(hm[nn][0][0], hm[nn][1][0]);
          float q1 = fmaxf(hm[nn][0][1], hm[nn][1][1]);
          const int c = ntp*32 + nn*16 + l15;
          const int k0 = c*196 + py*14 + px0;      // even
          *(unsigned int*)&h3m[(k0 >> 5)*512 + (k0 & 31)] = cvtpk(q0, q1);
        }
      }
      // rotate cache
      #pragma unroll
      for (int kx = 0; kx < 3; ++kx) { c0[kx] = r2[kx]; c1[kx] = r3[kx]; }
    }
  }
}

// ---------------- FC1 GEMM, fragment-layout operands, no LDS ----------------
// Every A/B fragment load = contiguous coalesced 1KB wave-load; full unroll
// so the compiler can hold ~dozens of loads in flight (VGPR cap 128 -> 4 w/SIMD).
__global__ __launch_bounds__(256, 4) void k_fc1(const unsigned short* __restrict__ h3,
                                                const unsigned short* __restrict__ fc1wb,
                                                float* __restrict__ h4p) {
  const int bid = blockIdx.x;            // 128 mtiles x 8 kh  (kh = XCD -> B L2-hot)
  const int mtile = bid >> 3, kh = bid & 7;
  const int t = threadIdx.x, lane = t & 63, w = t >> 6;
  const int l15 = lane & 15, lk = lane >> 4;
  const int lo = l15*32 + lk*8;          // fragment-internal offset (512 shorts)

  const unsigned short* ap  = h3    + (size_t)mtile*200704 + (size_t)(kh*49)*512 + lo;
  const unsigned short* b0p = fc1wb + (size_t)(kh*49)*4096 + (w*32)*32 + lo;

  f32x4 acc0 = {0.f,0.f,0.f,0.f}, acc1 = {0.f,0.f,0.f,0.f};
  #pragma unroll
  for (int ks = 0; ks < 49; ++ks) {
    bf16x8 a  = *(const bf16x8*)(ap  + ks*512);
    bf16x8 w0 = *(const bf16x8*)(b0p + ks*4096);
    bf16x8 w1 = *(const bf16x8*)(b0p + ks*4096 + 512);
    acc0 = __builtin_amdgcn_mfma_f32_16x16x32_bf16(a, w0, acc0, 0, 0, 0);
    acc1 = __builtin_amdgcn_mfma_f32_16x16x32_bf16(a, w1, acc1, 0, 0, 0);
  }
  float* outp = h4p + (size_t)kh * NB * 128;
  const int n0 = w*32 + l15;
  #pragma unroll
  for (int jj = 0; jj < 4; ++jj) {
    const int bb = mtile*16 + lk*4 + jj;
    outp[bb*128 + n0]      = acc0[jj];
    outp[bb*128 + n0 + 16] = acc1[jj];
  }
}

// ---------------- K-partial reduce + bias + relu + FC2 ----------------
__global__ __launch_bounds__(256) void k_fc2(const float* __restrict__ h4p,
                                             const float* __restrict__ fc1b,
                                             const float* __restrict__ fc2w,
                                             const float* __restrict__ fc2b,
                                             float* __restrict__ out) {
  __shared__ float hs[8*129];
  const int blk = blockIdx.x;    // 256 blocks x 8 batches
  const int t = threadIdx.x;
  for (int i = t; i < 1024; i += 256) {
    const int base = blk*1024 + i;
    float v = 0.f;
    #pragma unroll
    for (int kh = 0; kh < 8; ++kh) v += h4p[base + kh*262144];
    v += fc1b[i & 127];
    hs[(i >> 7)*129 + (i & 127)] = fmaxf(v, 0.f);
  }
  __syncthreads();
  if (t < 80) {
    const int bb = t / 10, n = t - (t/10)*10;
    float acc = fc2b[n];
    const float* wr = fc2w + n*128;
    const float* hr = hs + bb*129;
    #pragma unroll 8
    for (int k = 0; k < 128; ++k) acc = fmaf(hr[k], wr[k], acc);
    out[(blk*8 + bb)*10 + n] = acc;
  }
}

extern "C" void kernel_launch(void* const* d_in, const int* in_sizes, int n_in,
                              void* d_out, int out_size, void* d_ws, size_t ws_size,
                              hipStream_t stream) {
  const float* x    = (const float*)d_in[0];
  const float* w1   = (const float*)d_in[1];
  const float* p1   = (const float*)d_in[2];
  const float* p2   = (const float*)d_in[3];
  const float* b1   = (const float*)d_in[4];
  const float* w2   = (const float*)d_in[5];
  const float* b2   = (const float*)d_in[6];
  const float* fc1w = (const float*)d_in[7];
  const float* fc1b = (const float*)d_in[8];
  const float* fc2w = (const float*)d_in[9];
  const float* fc2b = (const float*)d_in[10];

  // ws layout (bytes):
  //        0: k1b bf16[32][32]             (2048)
  //     4096: w2b bf16[9][64][32]          (36864)
  //    40960: fc1wbF bf16[392][128][32]    (3211264)
  //  3252224: h3F bf16[128][392][16][32]   (51380224)
  // 54632448: h4p f32[8][2048][128]        (8388608)  -> total 63021056
  if (ws_size < 63021056u) return;
  char* ws = (char*)d_ws;
  unsigned short* k1b  = (unsigned short*)(ws + 0);
  unsigned short* w2b  = (unsigned short*)(ws + 4096);
  unsigned short* fc1wb= (unsigned short*)(ws + 40960);
  unsigned short* h3   = (unsigned short*)(ws + 3252224);
  float* h4p           = (float*)(ws + 54632448);

  k_prep<<<(401408 + 18432 + 1024 + 255) / 256, 256, 0, stream>>>(
      w2, fc1w, w1, p1, p2, w2b, fc1wb, k1b);
  k_conv<<<NB, 256, 0, stream>>>(x, k1b, b1, w2b, b2, h3);
  k_fc1<<<1024, 256, 0, stream>>>(h3, fc1wb, h4p);
  k_fc2<<<256, 256, 0, stream>>>(h4p, fc1b, fc2w, fc2b, (float*)d_out);
}

// Round 9
// 111.916 us; speedup vs baseline: 1.5487x; 1.0366x over previous
//
#include <hip/hip_runtime.h>
#include <hip/hip_bf16.h>

typedef __attribute__((ext_vector_type(8))) short bf16x8;
typedef __attribute__((ext_vector_type(4))) float f32x4;
typedef __attribute__((ext_vector_type(4))) unsigned int u32x4;
typedef __attribute__((ext_vector_type(2))) unsigned int u32x2;

#define NB 2048

static __device__ __forceinline__ unsigned short f2bf(float f) {
  unsigned int u = __builtin_bit_cast(unsigned int, f);
  u += 0x7fffu + ((u >> 16) & 1u);   // RNE
  return (unsigned short)(u >> 16);
}
// HW packed f32->bf16 (RNE), two values into one dword
static __device__ __forceinline__ unsigned int cvtpk(float lo, float hi) {
  unsigned int r;
  asm("v_cvt_pk_bf16_f32 %0, %1, %2" : "=v"(r) : "v"(lo), "v"(hi));
  return r;
}

// ---------------- weight prep (single pass) ----------------
// fc1wbF fragment layout: idx = q*4096 + n*32 + kw   (q=k>>5, kw=k&31)
__global__ __launch_bounds__(256) void k_prep(
    const float* __restrict__ w2, const float* __restrict__ fc1w,
    const float* __restrict__ w1, const float* __restrict__ p1,
    const float* __restrict__ p2,
    unsigned short* __restrict__ w2b, unsigned short* __restrict__ fc1wb,
    unsigned short* __restrict__ k1b) {
  const int gid = blockIdx.x * blockDim.x + threadIdx.x;
  if (gid < 401408) {
    const int j0 = gid * 4;               // 4 consecutive kw, same (q, n)
    const int kw = j0 & 31;
    const int n  = (j0 >> 5) & 127;
    const int q  = j0 >> 12;
    f32x4 v = *(const f32x4*)&fc1w[n*12544 + q*32 + kw];
    u32x2 r = { cvtpk(v[0], v[1]), cvtpk(v[2], v[3]) };
    *(u32x2*)&fc1wb[j0] = r;
  } else if (gid < 401408 + 18432) {
    int i = gid - 401408;
    int cin = i & 31;
    int cout = (i >> 5) & 63;
    int kk = i >> 11;          // 0..8
    int ky = kk / 3, kx = kk % 3;
    w2b[i] = f2bf(w2[((cout*32 + cin)*3 + ky)*3 + kx]);
  } else if (gid < 401408 + 18432 + 1024) {
    int t = gid - (401408 + 18432);  // 0..1023
    int o = t >> 5, tap = t & 31;
    unsigned short r = 0;
    if (tap < 25) {
      int a = tap / 5, bcol = tap % 5;
      float acc = 0.f;
      for (int k = 0; k < 26; ++k) {
        float q1 = p1[o*26 + k] + 2.0f;
        float q2 = p2[o*26 + k] + 2.0f;
        float f1 = floorf(q1), f2 = floorf(q2);
        int idx1 = (int)f1 + ((q1 - f1) >= 0.5f ? 1 : 0);
        int idx2 = (int)f2 + ((q2 - f2) >= 0.5f ? 1 : 0);
        if (idx1 == a && idx2 == bcol) acc += w1[o*26 + k];
      }
      r = f2bf(acc);
    }
    k1b[t] = r;
  }
}

// ---------------- fused conv1(MFMA)+relu -> conv2(MFMA)+relu+maxpool ----------------
// one block = one image; 3 blocks/CU (4 blocks/CU thrashes L2 write-combining —
// measured FETCH 3.4->38MB, WRITE 54->114MB; do NOT raise).
// XCD-swizzled grid: all 16 images of an h3F mtile land on ONE XCD so the
// mi-interleaved 128B lines complete within one L2.
// h1s layout: pixel-major, 4x 16B cin-blocks per pixel, XOR-swizzled.
// h3F OUTPUT fragment layout: idx = mtile*200704 + ks*512 + mi*32 + kw
__global__ __launch_bounds__(256, 3) void k_conv(
    const float* __restrict__ x, const unsigned short* __restrict__ k1b,
    const float* __restrict__ b1, const unsigned short* __restrict__ w2b,
    const float* __restrict__ b2, unsigned short* __restrict__ h3) {
  __shared__ __align__(16) float xs[32*36];              // padded input, stride 36
  __shared__ __align__(16) unsigned short h1s[16*32*32]; // one y-half, swizzled

  const int t = threadIdx.x;
  const int bimg = (blockIdx.x & 7) * 256 + (blockIdx.x >> 3);  // XCD-contiguous
  const int lane = t & 63;
  const int wid = t >> 6;
  const int l15 = lane & 15;
  const int lk = lane >> 4;

  // ---- stage x into xs (zero border) ----
  for (int i = t; i < 1152; i += 256) {
    int iy = i / 36, ix = i - iy*36;
    float v = 0.f;
    if (iy >= 2 && iy < 30 && ix >= 2 && ix < 30)
      v = x[bimg*784 + (iy-2)*28 + (ix-2)];
    xs[i] = v;
  }

  // ---- conv1 operands (registers) ----
  int off[8];                       // per-lane im2col tap offsets (taps>=25 clamp: A rows are 0 there)
  #pragma unroll
  for (int j = 0; j < 8; ++j) {
    int tp = lk*8 + j; tp = tp > 24 ? 24 : tp;
    int ky = tp / 5;
    off[j] = ky*36 + (tp - ky*5);
  }
  const bf16x8 k1a0 = *(const bf16x8*)&k1b[l15*32 + lk*8];
  const bf16x8 k1a1 = *(const bf16x8*)&k1b[(16 + l15)*32 + lk*8];
  f32x4 b1i0, b1i1;                 // MFMA acc-init with bias (row = cout = lk*4+reg)
  #pragma unroll
  for (int r = 0; r < 4; ++r) {
    b1i0[r] = b1[lk*4 + r];
    b1i1[r] = b1[16 + lk*4 + r];
  }

  // ---- conv2 operands (registers) ----
  const int ntp = wid & 1;      // couts ntp*32 .. ntp*32+31
  const int tx  = wid >> 1;     // x half-tile (wave-uniform)
  bf16x8 bfr[2][9];
  #pragma unroll
  for (int nn = 0; nn < 2; ++nn)
    #pragma unroll
    for (int kk = 0; kk < 9; ++kk)
      bfr[nn][kk] = *(const bf16x8*)&w2b[(kk*64 + (ntp*2+nn)*16 + l15)*32 + lk*8];
  f32x4 b2i[2];                 // acc-init (col = cout = l15, same across rows)
  #pragma unroll
  for (int nn = 0; nn < 2; ++nn) {
    float bb = b2[ntp*32 + nn*16 + l15];
    b2i[nn] = (f32x4){bb, bb, bb, bb};
  }
  int colOff[3];                // byte offsets into an h1s row (swizzle is row-independent)
  #pragma unroll
  for (int kx = 0; kx < 3; ++kx) {
    int xk = tx*16 + l15 + kx; xk = xk > 31 ? 31 : xk;   // clamped dummies read zero pads
    colOff[kx] = xk*64 + ((lk ^ ((xk >> 1) & 3)) << 4);
  }

  const int mtile = bimg >> 4, mi = bimg & 15;
  unsigned short* h3m = h3 + (size_t)mtile*200704 + mi*32;

  __syncthreads();

  for (int half = 0; half < 2; ++half) {
    if (half) __syncthreads();          // prev half's conv2 reads done

    // ---- zero pads for this half ----
    {
      u32x4* H = (u32x4*)h1s;
      u32x4 z = {0u,0u,0u,0u};
      const int zrow = half ? 15 : 0;   // full zero row (y'=0 / y'=29)
      if (t < 128) H[zrow*128 + t] = z;
      const int r0 = half ? 0 : 1;      // col pads on the 15 computed rows
      if (t < 240) {                    // 15 rows x 4 px x 4 chunks
        int rr = t >> 4, rem = t & 15;
        int pi = rem >> 2, sub = rem & 3;
        int px = pi == 0 ? 0 : 28 + pi; // x' in {0,29,30,31}
        H[((r0 + rr)*32 + px)*4 + sub] = z;
      }
    }

    // ---- conv1 via MFMA: A=k1[cout][tap], B=im2col[tap][pixel] ----
    const int ybase = half ? 13 : 0;
    for (int tid = wid; tid < 30; tid += 4) {
      const int ty = tid >> 1;                 // 0..14
      const int x0 = (tid & 1) << 4;
      const int yo = ybase + ty;               // conv output row
      const float* bp = &xs[yo*36 + x0 + l15];
      u32x4 bw;
      bw[0] = cvtpk(bp[off[0]], bp[off[1]]);
      bw[1] = cvtpk(bp[off[2]], bp[off[3]]);
      bw[2] = cvtpk(bp[off[4]], bp[off[5]]);
      bw[3] = cvtpk(bp[off[6]], bp[off[7]]);
      const bf16x8 bfrag = __builtin_bit_cast(bf16x8, bw);
      f32x4 d0 = b1i0, d1 = b1i1;
      d0 = __builtin_amdgcn_mfma_f32_16x16x32_bf16(k1a0, bfrag, d0, 0, 0, 0);
      d1 = __builtin_amdgcn_mfma_f32_16x16x32_bf16(k1a1, bfrag, d1, 0, 0, 0);
      // D: col=l15=pixel, row=lk*4+reg=cout -> 4 consecutive couts per lane
      const int xo = x0 + l15;
      if (xo < 28) {
        const int ry = half ? (yo - 13) : (yo + 1);
        const int pix = ry*32 + xo + 1;
        const int swz = (pix >> 1) & 3;
        const int blkbase = (lk >> 1);
        unsigned int w0lo = cvtpk(fmaxf(d0[0], 0.f), fmaxf(d0[1], 0.f));
        unsigned int w0hi = cvtpk(fmaxf(d0[2], 0.f), fmaxf(d0[3], 0.f));
        unsigned int w1lo = cvtpk(fmaxf(d1[0], 0.f), fmaxf(d1[1], 0.f));
        unsigned int w1hi = cvtpk(fmaxf(d1[2], 0.f), fmaxf(d1[3], 0.f));
        char* base = (char*)h1s + pix*64 + (lk & 1)*8;
        *(u32x2*)(base + ((blkbase ^ swz) << 4))       = (u32x2){w0lo, w0hi};
        *(u32x2*)(base + (((2 + blkbase) ^ swz) << 4)) = (u32x2){w1lo, w1hi};
      }
    }
    __syncthreads();

    // ---- conv2 via MFMA ----
    const char* h1c = (const char*)h1s;
    for (int pyl = 0; pyl < 7; ++pyl) {
      const int py = half*7 + pyl;
      const int rbase = pyl*2*2048;
      f32x4 acc[2][2];
      #pragma unroll
      for (int yi = 0; yi < 2; ++yi)
        #pragma unroll
        for (int nn = 0; nn < 2; ++nn) acc[yi][nn] = b2i[nn];
      #pragma unroll
      for (int kx = 0; kx < 3; ++kx) {
        bf16x8 af[4];
        #pragma unroll
        for (int r = 0; r < 4; ++r)
          af[r] = *(const bf16x8*)(h1c + rbase + r*2048 + colOff[kx]);
        #pragma unroll
        for (int ky = 0; ky < 3; ++ky)
          #pragma unroll
          for (int yi = 0; yi < 2; ++yi) {
            acc[yi][0] = __builtin_amdgcn_mfma_f32_16x16x32_bf16(af[yi+ky], bfr[0][ky*3+kx], acc[yi][0], 0, 0, 0);
            acc[yi][1] = __builtin_amdgcn_mfma_f32_16x16x32_bf16(af[yi+ky], bfr[1][ky*3+kx], acc[yi][1], 0, 0, 0);
          }
      }
      // relu + 2x2 maxpool in-register, write bf16 to fragment-layout h3
      float hm[2][2][2];   // [nn][yi][xpair]
      #pragma unroll
      for (int yi = 0; yi < 2; ++yi)
        #pragma unroll
        for (int nn = 0; nn < 2; ++nn) {
          float v0 = fmaxf(acc[yi][nn][0], 0.f);
          float v1 = fmaxf(acc[yi][nn][1], 0.f);
          float v2 = fmaxf(acc[yi][nn][2], 0.f);
          float v3 = fmaxf(acc[yi][nn][3], 0.f);
          hm[nn][yi][0] = fmaxf(v0, v1);
          hm[nn][yi][1] = fmaxf(v2, v3);
        }
      if (!(tx == 1 && lk == 3)) {                 // drop x>=28 dummy columns
        const int px0 = tx*8 + lk*2;
        #pragma unroll
        for (int nn = 0; nn < 2; ++nn) {
          float q0 = fmaxf(hm[nn][0][0], hm[nn][1][0]);
          float q1 = fmaxf(hm[nn][0][1], hm[nn][1][1]);
          const int c = ntp*32 + nn*16 + l15;
          const int k0 = c*196 + py*14 + px0;      // even
          *(unsigned int*)&h3m[(k0 >> 5)*512 + (k0 & 31)] = cvtpk(q0, q1);
        }
      }
    }
  }
}

// ---------------- FC1 GEMM, fragment-layout operands, no LDS ----------------
// 32-row blocks (2 A-frags): 4 MFMA per ks per wave, halves per-XCD L2 B-traffic
// vs 16-row blocks. Every load = contiguous coalesced 1KB wave-load.
__global__ __launch_bounds__(256, 2) void k_fc1(const unsigned short* __restrict__ h3,
                                                const unsigned short* __restrict__ fc1wb,
                                                float* __restrict__ h4p) {
  const int bid = blockIdx.x;            // 64 m2-tiles x 8 kh (kh = XCD -> B L2-hot)
  const int m2 = bid >> 3, kh = bid & 7;
  const int t = threadIdx.x, lane = t & 63, w = t >> 6;
  const int l15 = lane & 15, lk = lane >> 4;
  const int lo = l15*32 + lk*8;          // fragment-internal offset (512 shorts)

  const unsigned short* a0p = h3 + (size_t)(2*m2)*200704 + (size_t)(kh*49)*512 + lo;
  const unsigned short* a1p = a0p + 200704;
  const unsigned short* b0p = fc1wb + (size_t)(kh*49)*4096 + (w*32)*32 + lo;

  f32x4 acc00 = {0.f,0.f,0.f,0.f}, acc01 = {0.f,0.f,0.f,0.f};
  f32x4 acc10 = {0.f,0.f,0.f,0.f}, acc11 = {0.f,0.f,0.f,0.f};
  #pragma unroll 7
  for (int ks = 0; ks < 49; ++ks) {
    bf16x8 a0 = *(const bf16x8*)(a0p + ks*512);
    bf16x8 a1 = *(const bf16x8*)(a1p + ks*512);
    bf16x8 w0 = *(const bf16x8*)(b0p + ks*4096);
    bf16x8 w1 = *(const bf16x8*)(b0p + ks*4096 + 512);
    acc00 = __builtin_amdgcn_mfma_f32_16x16x32_bf16(a0, w0, acc00, 0, 0, 0);
    acc01 = __builtin_amdgcn_mfma_f32_16x16x32_bf16(a0, w1, acc01, 0, 0, 0);
    acc10 = __builtin_amdgcn_mfma_f32_16x16x32_bf16(a1, w0, acc10, 0, 0, 0);
    acc11 = __builtin_amdgcn_mfma_f32_16x16x32_bf16(a1, w1, acc11, 0, 0, 0);
  }
  float* outp = h4p + (size_t)kh * NB * 128;
  const int n0 = w*32 + l15;
  const int bb0 = m2*32 + lk*4;
  #pragma unroll
  for (int jj = 0; jj < 4; ++jj) {
    outp[(bb0 + jj)*128 + n0]           = acc00[jj];
    outp[(bb0 + jj)*128 + n0 + 16]      = acc01[jj];
    outp[(bb0 + 16 + jj)*128 + n0]      = acc10[jj];
    outp[(bb0 + 16 + jj)*128 + n0 + 16] = acc11[jj];
  }
}

// ---------------- K-partial reduce + bias + relu + FC2 ----------------
__global__ __launch_bounds__(256) void k_fc2(const float* __restrict__ h4p,
                                             const float* __restrict__ fc1b,
                                             const float* __restrict__ fc2w,
                                             const float* __restrict__ fc2b,
                                             float* __restrict__ out) {
  __shared__ float hs[8*129];
  const int blk = blockIdx.x;    // 256 blocks x 8 batches
  const int t = threadIdx.x;
  for (int i = t; i < 1024; i += 256) {
    const int base = blk*1024 + i;
    float v = 0.f;
    #pragma unroll
    for (int kh = 0; kh < 8; ++kh) v += h4p[base + kh*262144];
    v += fc1b[i & 127];
    hs[(i >> 7)*129 + (i & 127)] = fmaxf(v, 0.f);
  }
  __syncthreads();
  if (t < 80) {
    const int bb = t / 10, n = t - (t/10)*10;
    float acc = fc2b[n];
    const float* wr = fc2w + n*128;
    const float* hr = hs + bb*129;
    #pragma unroll 8
    for (int k = 0; k < 128; ++k) acc = fmaf(hr[k], wr[k], acc);
    out[(blk*8 + bb)*10 + n] = acc;
  }
}

extern "C" void kernel_launch(void* const* d_in, const int* in_sizes, int n_in,
                              void* d_out, int out_size, void* d_ws, size_t ws_size,
                              hipStream_t stream) {
  const float* x    = (const float*)d_in[0];
  const float* w1   = (const float*)d_in[1];
  const float* p1   = (const float*)d_in[2];
  const float* p2   = (const float*)d_in[3];
  const float* b1   = (const float*)d_in[4];
  const float* w2   = (const float*)d_in[5];
  const float* b2   = (const float*)d_in[6];
  const float* fc1w = (const float*)d_in[7];
  const float* fc1b = (const float*)d_in[8];
  const float* fc2w = (const float*)d_in[9];
  const float* fc2b = (const float*)d_in[10];

  // ws layout (bytes):
  //        0: k1b bf16[32][32]             (2048)
  //     4096: w2b bf16[9][64][32]          (36864)
  //    40960: fc1wbF bf16[392][128][32]    (3211264)
  //  3252224: h3F bf16[128][392][16][32]   (51380224)
  // 54632448: h4p f32[8][2048][128]        (8388608)  -> total 63021056
  if (ws_size < 63021056u) return;
  char* ws = (char*)d_ws;
  unsigned short* k1b  = (unsigned short*)(ws + 0);
  unsigned short* w2b  = (unsigned short*)(ws + 4096);
  unsigned short* fc1wb= (unsigned short*)(ws + 40960);
  unsigned short* h3   = (unsigned short*)(ws + 3252224);
  float* h4p           = (float*)(ws + 54632448);

  k_prep<<<(401408 + 18432 + 1024 + 255) / 256, 256, 0, stream>>>(
      w2, fc1w, w1, p1, p2, w2b, fc1wb, k1b);
  k_conv<<<NB, 256, 0, stream>>>(x, k1b, b1, w2b, b2, h3);
  k_fc1<<<512, 256, 0, stream>>>(h3, fc1wb, h4p);
  k_fc2<<<256, 256, 0, stream>>>(h4p, fc1b, fc2w, fc2b, (float*)d_out);
}

// Round 10
// 105.870 us; speedup vs baseline: 1.6371x; 1.0571x over previous
//
#include <hip/hip_runtime.h>
#include <hip/hip_bf16.h>

typedef __attribute__((ext_vector_type(8))) short bf16x8;
typedef __attribute__((ext_vector_type(4))) float f32x4;
typedef __attribute__((ext_vector_type(4))) unsigned int u32x4;
typedef __attribute__((ext_vector_type(2))) unsigned int u32x2;

#define NB 2048

static __device__ __forceinline__ unsigned short f2bf(float f) {
  unsigned int u = __builtin_bit_cast(unsigned int, f);
  u += 0x7fffu + ((u >> 16) & 1u);   // RNE
  return (unsigned short)(u >> 16);
}
// HW packed f32->bf16 (RNE), two values into one dword
static __device__ __forceinline__ unsigned int cvtpk(float lo, float hi) {
  unsigned int r;
  asm("v_cvt_pk_bf16_f32 %0, %1, %2" : "=v"(r) : "v"(lo), "v"(hi));
  return r;
}

// ---------------- weight prep (single pass) ----------------
// fc1wbF fragment layout: idx = q*4096 + n*32 + kw   (q=k>>5, kw=k&31)
__global__ __launch_bounds__(256) void k_prep(
    const float* __restrict__ w2, const float* __restrict__ fc1w,
    const float* __restrict__ w1, const float* __restrict__ p1,
    const float* __restrict__ p2,
    unsigned short* __restrict__ w2b, unsigned short* __restrict__ fc1wb,
    unsigned short* __restrict__ k1b) {
  const int gid = blockIdx.x * blockDim.x + threadIdx.x;
  if (gid < 401408) {
    const int j0 = gid * 4;               // 4 consecutive kw, same (q, n)
    const int kw = j0 & 31;
    const int n  = (j0 >> 5) & 127;
    const int q  = j0 >> 12;
    f32x4 v = *(const f32x4*)&fc1w[n*12544 + q*32 + kw];
    u32x2 r = { cvtpk(v[0], v[1]), cvtpk(v[2], v[3]) };
    *(u32x2*)&fc1wb[j0] = r;
  } else if (gid < 401408 + 18432) {
    int i = gid - 401408;
    int cin = i & 31;
    int cout = (i >> 5) & 63;
    int kk = i >> 11;          // 0..8
    int ky = kk / 3, kx = kk % 3;
    w2b[i] = f2bf(w2[((cout*32 + cin)*3 + ky)*3 + kx]);
  } else if (gid < 401408 + 18432 + 1024) {
    int t = gid - (401408 + 18432);  // 0..1023
    int o = t >> 5, tap = t & 31;
    unsigned short r = 0;
    if (tap < 25) {
      int a = tap / 5, bcol = tap % 5;
      float acc = 0.f;
      for (int k = 0; k < 26; ++k) {
        float q1 = p1[o*26 + k] + 2.0f;
        float q2 = p2[o*26 + k] + 2.0f;
        float f1 = floorf(q1), f2 = floorf(q2);
        int idx1 = (int)f1 + ((q1 - f1) >= 0.5f ? 1 : 0);
        int idx2 = (int)f2 + ((q2 - f2) >= 0.5f ? 1 : 0);
        if (idx1 == a && idx2 == bcol) acc += w1[o*26 + k];
      }
      r = f2bf(acc);
    }
    k1b[t] = r;
  }
}

// ---------------- fused conv1(MFMA)+relu -> conv2(MFMA)+relu+maxpool ----------------
// one block = one image; 3 blocks/CU (4 blocks/CU thrashes L2 write-combining —
// measured FETCH 3.4->38MB, WRITE 54->114MB; do NOT raise).
// XCD-swizzled grid: all 16 images of an h3F mtile land on ONE XCD so the
// mi-interleaved 128B lines complete within one L2.
// h1s layout: pixel-major, 4x 16B cin-blocks per pixel, XOR-swizzled.
// h3F OUTPUT fragment layout: idx = mtile*200704 + ks*512 + mi*32 + kw
__global__ __launch_bounds__(256, 3) void k_conv(
    const float* __restrict__ x, const unsigned short* __restrict__ k1b,
    const float* __restrict__ b1, const unsigned short* __restrict__ w2b,
    const float* __restrict__ b2, unsigned short* __restrict__ h3) {
  __shared__ __align__(16) float xs[32*36];              // padded input, stride 36
  __shared__ __align__(16) unsigned short h1s[16*32*32]; // one y-half, swizzled

  const int t = threadIdx.x;
  const int bimg = (blockIdx.x & 7) * 256 + (blockIdx.x >> 3);  // XCD-contiguous
  const int lane = t & 63;
  const int wid = t >> 6;
  const int l15 = lane & 15;
  const int lk = lane >> 4;

  // ---- stage x into xs (zero border) ----
  for (int i = t; i < 1152; i += 256) {
    int iy = i / 36, ix = i - iy*36;
    float v = 0.f;
    if (iy >= 2 && iy < 30 && ix >= 2 && ix < 30)
      v = x[bimg*784 + (iy-2)*28 + (ix-2)];
    xs[i] = v;
  }

  // ---- conv1 operands (registers) ----
  int off[8];                       // per-lane im2col tap offsets (taps>=25 clamp: A rows are 0 there)
  #pragma unroll
  for (int j = 0; j < 8; ++j) {
    int tp = lk*8 + j; tp = tp > 24 ? 24 : tp;
    int ky = tp / 5;
    off[j] = ky*36 + (tp - ky*5);
  }
  const bf16x8 k1a0 = *(const bf16x8*)&k1b[l15*32 + lk*8];
  const bf16x8 k1a1 = *(const bf16x8*)&k1b[(16 + l15)*32 + lk*8];
  f32x4 b1i0, b1i1;                 // MFMA acc-init with bias (row = cout = lk*4+reg)
  #pragma unroll
  for (int r = 0; r < 4; ++r) {
    b1i0[r] = b1[lk*4 + r];
    b1i1[r] = b1[16 + lk*4 + r];
  }

  // ---- conv2 operands (registers) ----
  const int ntp = wid & 1;      // couts ntp*32 .. ntp*32+31
  const int tx  = wid >> 1;     // x half-tile (wave-uniform)
  bf16x8 bfr[2][9];
  #pragma unroll
  for (int nn = 0; nn < 2; ++nn)
    #pragma unroll
    for (int kk = 0; kk < 9; ++kk)
      bfr[nn][kk] = *(const bf16x8*)&w2b[(kk*64 + (ntp*2+nn)*16 + l15)*32 + lk*8];
  f32x4 b2i[2];                 // acc-init (col = cout = l15, same across rows)
  #pragma unroll
  for (int nn = 0; nn < 2; ++nn) {
    float bb = b2[ntp*32 + nn*16 + l15];
    b2i[nn] = (f32x4){bb, bb, bb, bb};
  }
  int colOff[3];                // byte offsets into an h1s row (swizzle is row-independent)
  #pragma unroll
  for (int kx = 0; kx < 3; ++kx) {
    int xk = tx*16 + l15 + kx; xk = xk > 31 ? 31 : xk;   // clamped dummies read zero pads
    colOff[kx] = xk*64 + ((lk ^ ((xk >> 1) & 3)) << 4);
  }

  const int mtile = bimg >> 4, mi = bimg & 15;
  unsigned short* h3m = h3 + (size_t)mtile*200704 + mi*32;

  __syncthreads();

  for (int half = 0; half < 2; ++half) {
    if (half) __syncthreads();          // prev half's conv2 reads done

    // ---- zero pads for this half ----
    {
      u32x4* H = (u32x4*)h1s;
      u32x4 z = {0u,0u,0u,0u};
      const int zrow = half ? 15 : 0;   // full zero row (y'=0 / y'=29)
      if (t < 128) H[zrow*128 + t] = z;
      const int r0 = half ? 0 : 1;      // col pads on the 15 computed rows
      if (t < 240) {                    // 15 rows x 4 px x 4 chunks
        int rr = t >> 4, rem = t & 15;
        int pi = rem >> 2, sub = rem & 3;
        int px = pi == 0 ? 0 : 28 + pi; // x' in {0,29,30,31}
        H[((r0 + rr)*32 + px)*4 + sub] = z;
      }
    }

    // ---- conv1 via MFMA: A=k1[cout][tap], B=im2col[tap][pixel] ----
    const int ybase = half ? 13 : 0;
    for (int tid = wid; tid < 30; tid += 4) {
      const int ty = tid >> 1;                 // 0..14
      const int x0 = (tid & 1) << 4;
      const int yo = ybase + ty;               // conv output row
      const float* bp = &xs[yo*36 + x0 + l15];
      u32x4 bw;
      bw[0] = cvtpk(bp[off[0]], bp[off[1]]);
      bw[1] = cvtpk(bp[off[2]], bp[off[3]]);
      bw[2] = cvtpk(bp[off[4]], bp[off[5]]);
      bw[3] = cvtpk(bp[off[6]], bp[off[7]]);
      const bf16x8 bfrag = __builtin_bit_cast(bf16x8, bw);
      f32x4 d0 = b1i0, d1 = b1i1;
      d0 = __builtin_amdgcn_mfma_f32_16x16x32_bf16(k1a0, bfrag, d0, 0, 0, 0);
      d1 = __builtin_amdgcn_mfma_f32_16x16x32_bf16(k1a1, bfrag, d1, 0, 0, 0);
      // D: col=l15=pixel, row=lk*4+reg=cout -> 4 consecutive couts per lane
      const int xo = x0 + l15;
      if (xo < 28) {
        const int ry = half ? (yo - 13) : (yo + 1);
        const int pix = ry*32 + xo + 1;
        const int swz = (pix >> 1) & 3;
        const int blkbase = (lk >> 1);
        unsigned int w0lo = cvtpk(fmaxf(d0[0], 0.f), fmaxf(d0[1], 0.f));
        unsigned int w0hi = cvtpk(fmaxf(d0[2], 0.f), fmaxf(d0[3], 0.f));
        unsigned int w1lo = cvtpk(fmaxf(d1[0], 0.f), fmaxf(d1[1], 0.f));
        unsigned int w1hi = cvtpk(fmaxf(d1[2], 0.f), fmaxf(d1[3], 0.f));
        char* base = (char*)h1s + pix*64 + (lk & 1)*8;
        *(u32x2*)(base + ((blkbase ^ swz) << 4))       = (u32x2){w0lo, w0hi};
        *(u32x2*)(base + (((2 + blkbase) ^ swz) << 4)) = (u32x2){w1lo, w1hi};
      }
    }
    __syncthreads();

    // ---- conv2 via MFMA ----
    const char* h1c = (const char*)h1s;
    for (int pyl = 0; pyl < 7; ++pyl) {
      const int py = half*7 + pyl;
      const int rbase = pyl*2*2048;
      f32x4 acc[2][2];
      #pragma unroll
      for (int yi = 0; yi < 2; ++yi)
        #pragma unroll
        for (int nn = 0; nn < 2; ++nn) acc[yi][nn] = b2i[nn];
      #pragma unroll
      for (int kx = 0; kx < 3; ++kx) {
        bf16x8 af[4];
        #pragma unroll
        for (int r = 0; r < 4; ++r)
          af[r] = *(const bf16x8*)(h1c + rbase + r*2048 + colOff[kx]);
        #pragma unroll
        for (int ky = 0; ky < 3; ++ky)
          #pragma unroll
          for (int yi = 0; yi < 2; ++yi) {
            acc[yi][0] = __builtin_amdgcn_mfma_f32_16x16x32_bf16(af[yi+ky], bfr[0][ky*3+kx], acc[yi][0], 0, 0, 0);
            acc[yi][1] = __builtin_amdgcn_mfma_f32_16x16x32_bf16(af[yi+ky], bfr[1][ky*3+kx], acc[yi][1], 0, 0, 0);
          }
      }
      // pool-then-relu (monotonic: max(relu(..)) == relu(max(..))), only on
      // storing lanes: 7 fmax per nn (compiler fuses to v_max3) vs 14.
      if (!(tx == 1 && lk == 3)) {                 // drop x>=28 dummy columns
        const int px0 = tx*8 + lk*2;
        #pragma unroll
        for (int nn = 0; nn < 2; ++nn) {
          float q0 = fmaxf(fmaxf(fmaxf(acc[0][nn][0], acc[0][nn][1]),
                                 fmaxf(acc[1][nn][0], acc[1][nn][1])), 0.f);
          float q1 = fmaxf(fmaxf(fmaxf(acc[0][nn][2], acc[0][nn][3]),
                                 fmaxf(acc[1][nn][2], acc[1][nn][3])), 0.f);
          const int c = ntp*32 + nn*16 + l15;
          const int k0 = c*196 + py*14 + px0;      // even
          *(unsigned int*)&h3m[(k0 >> 5)*512 + (k0 & 31)] = cvtpk(q0, q1);
        }
      }
    }
  }
}

// ---------------- FC1 GEMM, fragment-layout operands, no LDS ----------------
// 32-row blocks (2 A-frags): 4 MFMA per ks per wave. FULL unroll at
// launch_bounds(256,2): ~200 free VGPRs of pending-load destinations so the
// scheduler keeps ~40+ dwordx4 loads in flight (covers ~900cyc HBM latency;
// unroll-7's 28-load window did not).
__global__ __launch_bounds__(256, 2) void k_fc1(const unsigned short* __restrict__ h3,
                                                const unsigned short* __restrict__ fc1wb,
                                                float* __restrict__ h4p) {
  const int bid = blockIdx.x;            // 64 m2-tiles x 8 kh (kh = XCD -> B L2-hot)
  const int m2 = bid >> 3, kh = bid & 7;
  const int t = threadIdx.x, lane = t & 63, w = t >> 6;
  const int l15 = lane & 15, lk = lane >> 4;
  const int lo = l15*32 + lk*8;          // fragment-internal offset (512 shorts)

  const unsigned short* a0p = h3 + (size_t)(2*m2)*200704 + (size_t)(kh*49)*512 + lo;
  const unsigned short* a1p = a0p + 200704;
  const unsigned short* b0p = fc1wb + (size_t)(kh*49)*4096 + (w*32)*32 + lo;

  f32x4 acc00 = {0.f,0.f,0.f,0.f}, acc01 = {0.f,0.f,0.f,0.f};
  f32x4 acc10 = {0.f,0.f,0.f,0.f}, acc11 = {0.f,0.f,0.f,0.f};
  #pragma unroll
  for (int ks = 0; ks < 49; ++ks) {
    bf16x8 a0 = *(const bf16x8*)(a0p + ks*512);
    bf16x8 a1 = *(const bf16x8*)(a1p + ks*512);
    bf16x8 w0 = *(const bf16x8*)(b0p + ks*4096);
    bf16x8 w1 = *(const bf16x8*)(b0p + ks*4096 + 512);
    acc00 = __builtin_amdgcn_mfma_f32_16x16x32_bf16(a0, w0, acc00, 0, 0, 0);
    acc01 = __builtin_amdgcn_mfma_f32_16x16x32_bf16(a0, w1, acc01, 0, 0, 0);
    acc10 = __builtin_amdgcn_mfma_f32_16x16x32_bf16(a1, w0, acc10, 0, 0, 0);
    acc11 = __builtin_amdgcn_mfma_f32_16x16x32_bf16(a1, w1, acc11, 0, 0, 0);
  }
  float* outp = h4p + (size_t)kh * NB * 128;
  const int n0 = w*32 + l15;
  const int bb0 = m2*32 + lk*4;
  #pragma unroll
  for (int jj = 0; jj < 4; ++jj) {
    outp[(bb0 + jj)*128 + n0]           = acc00[jj];
    outp[(bb0 + jj)*128 + n0 + 16]      = acc01[jj];
    outp[(bb0 + 16 + jj)*128 + n0]      = acc10[jj];
    outp[(bb0 + 16 + jj)*128 + n0 + 16] = acc11[jj];
  }
}

// ---------------- K-partial reduce + bias + relu + FC2 ----------------
__global__ __launch_bounds__(256) void k_fc2(const float* __restrict__ h4p,
                                             const float* __restrict__ fc1b,
                                             const float* __restrict__ fc2w,
                                             const float* __restrict__ fc2b,
                                             float* __restrict__ out) {
  __shared__ float hs[8*129];
  const int blk = blockIdx.x;    // 256 blocks x 8 batches
  const int t = threadIdx.x;
  for (int i = t; i < 1024; i += 256) {
    const int base = blk*1024 + i;
    float v = 0.f;
    #pragma unroll
    for (int kh = 0; kh < 8; ++kh) v += h4p[base + kh*262144];
    v += fc1b[i & 127];
    hs[(i >> 7)*129 + (i & 127)] = fmaxf(v, 0.f);
  }
  __syncthreads();
  if (t < 80) {
    const int bb = t / 10, n = t - (t/10)*10;
    float acc = fc2b[n];
    const float* wr = fc2w + n*128;
    const float* hr = hs + bb*129;
    #pragma unroll 8
    for (int k = 0; k < 128; ++k) acc = fmaf(hr[k], wr[k], acc);
    out[(blk*8 + bb)*10 + n] = acc;
  }
}

extern "C" void kernel_launch(void* const* d_in, const int* in_sizes, int n_in,
                              void* d_out, int out_size, void* d_ws, size_t ws_size,
                              hipStream_t stream) {
  const float* x    = (const float*)d_in[0];
  const float* w1   = (const float*)d_in[1];
  const float* p1   = (const float*)d_in[2];
  const float* p2   = (const float*)d_in[3];
  const float* b1   = (const float*)d_in[4];
  const float* w2   = (const float*)d_in[5];
  const float* b2   = (const float*)d_in[6];
  const float* fc1w = (const float*)d_in[7];
  const float* fc1b = (const float*)d_in[8];
  const float* fc2w = (const float*)d_in[9];
  const float* fc2b = (const float*)d_in[10];

  // ws layout (bytes):
  //        0: k1b bf16[32][32]             (2048)
  //     4096: w2b bf16[9][64][32]          (36864)
  //    40960: fc1wbF bf16[392][128][32]    (3211264)
  //  3252224: h3F bf16[128][392][16][32]   (51380224)
  // 54632448: h4p f32[8][2048][128]        (8388608)  -> total 63021056
  if (ws_size < 63021056u) return;
  char* ws = (char*)d_ws;
  unsigned short* k1b  = (unsigned short*)(ws + 0);
  unsigned short* w2b  = (unsigned short*)(ws + 4096);
  unsigned short* fc1wb= (unsigned short*)(ws + 40960);
  unsigned short* h3   = (unsigned short*)(ws + 3252224);
  float* h4p           = (float*)(ws + 54632448);

  k_prep<<<(401408 + 18432 + 1024 + 255) / 256, 256, 0, stream>>>(
      w2, fc1w, w1, p1, p2, w2b, fc1wb, k1b);
  k_conv<<<NB, 256, 0, stream>>>(x, k1b, b1, w2b, b2, h3);
  k_fc1<<<512, 256, 0, stream>>>(h3, fc1wb, h4p);
  k_fc2<<<256, 256, 0, stream>>>(h4p, fc1b, fc2w, fc2b, (float*)d_out);
}